// Round 1
// baseline (304.100 us; speedup 1.0000x reference)
//
#include <hip/hip_runtime.h>
#include <hip/hip_bf16.h>
#include <math.h>

// Problem constants (match reference)
#define BB 2
#define LL 4096
#define DD 128
#define ED 256
#define NN 16
#define KK 4
#define RR 8
#define HH 256
#define NT (BB*LL)          // 8192 tokens
#define NC 64               // chunks for scan
#define LC 64               // chunk length (NC*LC == LL)

// ---------------------------------------------------------------------------
// LayerNorm (optionally applied twice: inner_ln(norm1(x))). One token per
// block, 128 threads (=2 waves), shuffle+LDS reduction.
// ---------------------------------------------------------------------------
template<bool DOUBLE>
__global__ __launch_bounds__(128) void ln_k(const float* __restrict__ x,
    const float* __restrict__ g1, const float* __restrict__ b1,
    const float* __restrict__ g2, const float* __restrict__ b2,
    float* __restrict__ out) {
  const int token = blockIdx.x;
  const int d = threadIdx.x;
  __shared__ float sh[2];
  float v = x[(size_t)token*DD + d];

  auto redsum = [&](float val) -> float {
    #pragma unroll
    for (int m = 32; m; m >>= 1) val += __shfl_xor(val, m);
    if ((d & 63) == 0) sh[d >> 6] = val;
    __syncthreads();
    float r = sh[0] + sh[1];
    __syncthreads();
    return r;
  };

  float mean = redsum(v) * (1.f/128.f);
  float c = v - mean;
  float var = redsum(c*c) * (1.f/128.f);
  float y = c * rsqrtf(var + 1e-5f) * g1[d] + b1[d];
  if constexpr (DOUBLE) {
    float m2 = redsum(y) * (1.f/128.f);
    float c2 = y - m2;
    float v2 = redsum(c2*c2) * (1.f/128.f);
    y = c2 * rsqrtf(v2 + 1e-5f) * g2[d] + b2[d];
  }
  out[(size_t)token*DD + d] = y;
}

// ---------------------------------------------------------------------------
// Tiled fp32 GEMM: C[M,Nn] = A[M,KD] @ Bw[Nn,KD]^T  (weights stored [out,in])
// 64x64 tile, BK=16, 256 threads, 4x4 micro-tile per thread.
// EPI: 0 = none; 1 = +res; 2 = gelu(+bias); 3 = +bias +res
// ---------------------------------------------------------------------------
template<int KD, int EPI>
__global__ __launch_bounds__(256) void gemm_k(const float* __restrict__ A,
    const float* __restrict__ Bw, const float* __restrict__ bias,
    const float* __restrict__ res, float* __restrict__ C, int Nn) {
  __shared__ float As[16][68];
  __shared__ float Bs[16][68];
  const int row0 = blockIdx.y * 64;
  const int col0 = blockIdx.x * 64;
  const int tid = threadIdx.x;
  const int lm  = tid >> 2;          // 0..63 row within tile (loading)
  const int lk4 = (tid & 3) * 4;     // k sub-offset (float4)
  const int tm  = (tid >> 4) * 4;    // 0..60
  const int tn  = (tid & 15) * 4;    // 0..60

  float acc[4][4] = {};

  for (int k0 = 0; k0 < KD; k0 += 16) {
    const float4 av = *(const float4*)(A  + (size_t)(row0 + lm)*KD + k0 + lk4);
    const float4 bv = *(const float4*)(Bw + (size_t)(col0 + lm)*KD + k0 + lk4);
    __syncthreads();
    As[lk4+0][lm] = av.x; As[lk4+1][lm] = av.y;
    As[lk4+2][lm] = av.z; As[lk4+3][lm] = av.w;
    Bs[lk4+0][lm] = bv.x; Bs[lk4+1][lm] = bv.y;
    Bs[lk4+2][lm] = bv.z; Bs[lk4+3][lm] = bv.w;
    __syncthreads();
    #pragma unroll
    for (int k = 0; k < 16; k++) {
      const float4 a = *(const float4*)&As[k][tm];
      const float4 b = *(const float4*)&Bs[k][tn];
      acc[0][0] += a.x*b.x; acc[0][1] += a.x*b.y; acc[0][2] += a.x*b.z; acc[0][3] += a.x*b.w;
      acc[1][0] += a.y*b.x; acc[1][1] += a.y*b.y; acc[1][2] += a.y*b.z; acc[1][3] += a.y*b.w;
      acc[2][0] += a.z*b.x; acc[2][1] += a.z*b.y; acc[2][2] += a.z*b.z; acc[2][3] += a.z*b.w;
      acc[3][0] += a.w*b.x; acc[3][1] += a.w*b.y; acc[3][2] += a.w*b.z; acc[3][3] += a.w*b.w;
    }
  }

  #pragma unroll
  for (int i = 0; i < 4; i++) {
    const int row = row0 + tm + i;
    const int col = col0 + tn;
    float4 v = make_float4(acc[i][0], acc[i][1], acc[i][2], acc[i][3]);
    if constexpr (EPI == 2 || EPI == 3) {
      const float4 bb4 = *(const float4*)(bias + col);
      v.x += bb4.x; v.y += bb4.y; v.z += bb4.z; v.w += bb4.w;
    }
    if constexpr (EPI == 2) {
      v.x = 0.5f*v.x*(1.f + erff(v.x*0.70710678118f));
      v.y = 0.5f*v.y*(1.f + erff(v.y*0.70710678118f));
      v.z = 0.5f*v.z*(1.f + erff(v.z*0.70710678118f));
      v.w = 0.5f*v.w*(1.f + erff(v.w*0.70710678118f));
    }
    const size_t o = (size_t)row*Nn + col;
    if constexpr (EPI == 1 || EPI == 3) {
      const float4 r4 = *(const float4*)(res + o);
      v.x += r4.x; v.y += r4.y; v.z += r4.z; v.w += r4.w;
    }
    *(float4*)(C + o) = v;
  }
}

// ---------------------------------------------------------------------------
// Causal depthwise conv (K=4) + bias + silu. u lives inside xz (stride 512,
// cols 0..255). Output uc [NT, ED].
// ---------------------------------------------------------------------------
__global__ __launch_bounds__(256) void conv_k(const float* __restrict__ xz,
    const float* __restrict__ cw, const float* __restrict__ cb,
    float* __restrict__ uc) {
  const int token = blockIdx.x;
  const int e = threadIdx.x;
  const int b = token >> 12;       // /4096
  const int l = token & 4095;
  const float4 w = *(const float4*)(cw + e*4);
  float acc = cb[e];
  const float wv[4] = {w.x, w.y, w.z, w.w};
  #pragma unroll
  for (int k = 0; k < 4; k++) {
    const int ls = l - 3 + k;
    if (ls >= 0) acc += xz[((size_t)(b*LL + ls))*(2*ED) + e] * wv[k];
  }
  uc[(size_t)token*ED + e] = acc / (1.f + expf(-acc));   // silu
}

// ---------------------------------------------------------------------------
// x_proj: dbc[t, r] = sum_e uc[t,e] * w[r,e], r < 40. 32 tokens per block.
// ---------------------------------------------------------------------------
__global__ __launch_bounds__(256) void xproj_k(const float* __restrict__ uc,
    const float* __restrict__ w, float* __restrict__ dbc) {
  const int t0 = blockIdx.x * 32;
  __shared__ float su[32][ED];
  const float4* src = (const float4*)(uc + (size_t)t0*ED);
  float4* dst = (float4*)(&su[0][0]);
  #pragma unroll
  for (int i = 0; i < 8; i++) dst[threadIdx.x + i*256] = src[threadIdx.x + i*256];
  __syncthreads();
  #pragma unroll
  for (int i = 0; i < 5; i++) {
    const int o = threadIdx.x + i*256;   // 0..1279 = 32 tokens x 40 outputs
    const int tl = o / 40, r = o - tl*40;
    const float4* u4 = (const float4*)(&su[tl][0]);
    const float4* w4 = (const float4*)(w + (size_t)r*ED);
    float acc = 0.f;
    #pragma unroll 8
    for (int k = 0; k < ED/4; k++) {
      const float4 a = u4[k], b = w4[k];
      acc += a.x*b.x + a.y*b.y + a.z*b.z + a.w*b.w;
    }
    dbc[(size_t)(t0 + tl)*40 + r] = acc;
  }
}

// ---------------------------------------------------------------------------
// delta[t,e] = softplus(sum_r dt[t,r]*dt_w[e,r] + dt_b[e])
// ---------------------------------------------------------------------------
__global__ __launch_bounds__(256) void delta_k(const float* __restrict__ dbc,
    const float* __restrict__ dtw, const float* __restrict__ dtb,
    float* __restrict__ delta) {
  const int token = blockIdx.x;
  const int e = threadIdx.x;
  __shared__ float dt[RR];
  if (threadIdx.x < RR) dt[threadIdx.x] = dbc[(size_t)token*40 + threadIdx.x];
  __syncthreads();
  const float4 w0 = *(const float4*)(dtw + e*RR);
  const float4 w1 = *(const float4*)(dtw + e*RR + 4);
  float acc = dtb[e]
      + dt[0]*w0.x + dt[1]*w0.y + dt[2]*w0.z + dt[3]*w0.w
      + dt[4]*w1.x + dt[5]*w1.y + dt[6]*w1.z + dt[7]*w1.w;
  delta[(size_t)token*ED + e] = (acc > 20.f) ? acc : log1pf(expf(acc));
}

// ---------------------------------------------------------------------------
// Scan phase 1: per-chunk cumulative (prodA, h_end).
// grid (eg=16, c=64, b=2); threads: tid = eo*16 + n (e = eg*16+eo).
// chunk arrays layout: idx = ((c*B + b)*N + n)*ED + e
// ---------------------------------------------------------------------------
__global__ __launch_bounds__(256) void scan1_k(const float* __restrict__ delta,
    const float* __restrict__ uc, const float* __restrict__ dbc,
    const float* __restrict__ A_log, float* __restrict__ cA,
    float* __restrict__ cH) {
  const int eg = blockIdx.x, c = blockIdx.y, b = blockIdx.z;
  const int tid = threadIdx.x;
  const int eo = tid >> 4, n = tid & 15;
  const int e = eg*16 + eo;
  const float Aen = -expf(A_log[e*NN + n]);
  float h = 0.f, p = 1.f;
  const size_t tok0 = (size_t)b*LL + (size_t)c*LC;
  for (int i = 0; i < LC; i++) {
    const size_t t = tok0 + i;
    const float dv = delta[t*ED + e];
    const float uv = uc[t*ED + e];
    const float Bn = dbc[t*40 + RR + n];
    const float dA = expf(dv * Aen);
    h = dA*h + dv*Bn*uv;
    p *= dA;
  }
  const size_t idx = ((((size_t)c*BB + b)*NN + n)*ED + e);
  cA[idx] = p;
  cH[idx] = h;
}

// ---------------------------------------------------------------------------
// Scan phase 2: scan over the 64 chunk summaries. 8192 threads.
// ---------------------------------------------------------------------------
__global__ __launch_bounds__(256) void scan2_k(const float* __restrict__ cA,
    const float* __restrict__ cH, float* __restrict__ cP) {
  const int gt = blockIdx.x*256 + threadIdx.x;   // (b,n,e)
  const int b = gt >> 12, n = (gt >> 8) & 15, e = gt & 255;
  const size_t base = (((size_t)b*NN + n)*ED + e);
  float h = 0.f;
  for (int c = 0; c < NC; c++) {
    const size_t idx = (size_t)c*(BB*NN*ED) + base;
    cP[idx] = h;
    h = cA[idx]*h + cH[idx];
  }
}

// ---------------------------------------------------------------------------
// Scan phase 3: replay in-chunk with prefix, reduce over n, fuse gating:
// y = (scan_y + u*Dp) * silu(z)
// ---------------------------------------------------------------------------
__global__ __launch_bounds__(256) void scan3_k(const float* __restrict__ delta,
    const float* __restrict__ uc, const float* __restrict__ dbc,
    const float* __restrict__ xz, const float* __restrict__ A_log,
    const float* __restrict__ Dpv, const float* __restrict__ cP,
    float* __restrict__ y) {
  const int eg = blockIdx.x, c = blockIdx.y, b = blockIdx.z;
  const int tid = threadIdx.x;
  const int eo = tid >> 4, n = tid & 15;
  const int e = eg*16 + eo;
  const float Aen = -expf(A_log[e*NN + n]);
  const float Dpe = Dpv[e];
  float h = cP[((((size_t)c*BB + b)*NN + n)*ED + e)];
  const size_t tok0 = (size_t)b*LL + (size_t)c*LC;
  for (int i = 0; i < LC; i++) {
    const size_t t = tok0 + i;
    const float dv = delta[t*ED + e];
    const float uv = uc[t*ED + e];
    const float Bn = dbc[t*40 + RR + n];
    const float Cn = dbc[t*40 + RR + NN + n];
    const float dA = expf(dv * Aen);
    h = dA*h + dv*Bn*uv;
    float part = h * Cn;
    #pragma unroll
    for (int m = 1; m < 16; m <<= 1) part += __shfl_xor(part, m);
    if (n == 0) {
      const float zv = xz[t*(2*ED) + ED + e];
      const float g = zv / (1.f + expf(-zv));     // silu(z)
      y[t*ED + e] = (part + uv*Dpe) * g;
    }
  }
}

// ---------------------------------------------------------------------------
extern "C" void kernel_launch(void* const* d_in, const int* in_sizes, int n_in,
                              void* d_out, int out_size, void* d_ws, size_t ws_size,
                              hipStream_t stream) {
  const float* x      = (const float*)d_in[0];
  const float* n1g    = (const float*)d_in[1];
  const float* n1b    = (const float*)d_in[2];
  const float* ing    = (const float*)d_in[3];
  const float* inb    = (const float*)d_in[4];
  const float* in_w   = (const float*)d_in[5];
  const float* conv_w = (const float*)d_in[6];
  const float* conv_b = (const float*)d_in[7];
  const float* xproj_w= (const float*)d_in[8];
  const float* dt_w   = (const float*)d_in[9];
  const float* dt_b   = (const float*)d_in[10];
  const float* A_log  = (const float*)d_in[11];
  const float* Dpv    = (const float*)d_in[12];
  const float* out_w  = (const float*)d_in[13];
  const float* fc1_w  = (const float*)d_in[14];
  const float* fc1_b  = (const float*)d_in[15];
  const float* fc2_w  = (const float*)d_in[16];
  const float* fc2_b  = (const float*)d_in[17];
  float* out = (float*)d_out;

  // Workspace layout (floats). Peak ~54 MB.
  float* ws    = (float*)d_ws;
  float* xn    = ws;                         // [NT, DD]        1,048,576
  float* xz    = xn    + (size_t)NT*DD;      // [NT, 2*ED]      4,194,304
  float* uc    = xz    + (size_t)NT*2*ED;    // [NT, ED]        2,097,152
  float* dbc   = uc    + (size_t)NT*ED;      // [NT, 40]          327,680
  float* delta = dbc   + (size_t)NT*40;      // [NT, ED]        2,097,152
  float* cA    = delta + (size_t)NT*ED;      // [NC,B,N,ED]       524,288
  float* cH    = cA    + (size_t)NC*BB*NN*ED;//                   524,288
  float* cP    = cH    + (size_t)NC*BB*NN*ED;//                   524,288
  float* y     = cP    + (size_t)NC*BB*NN*ED;// [NT, ED]        2,097,152
  float* xnew  = xn;      // alias: xn dead after in_proj GEMM
  float* hln   = cA;      // alias: chunk arrays dead after phase 3
  float* hmlp  = delta;   // alias: delta dead after phase 3

  // 1) xn = inner_ln(norm1(x))
  ln_k<true><<<NT, 128, 0, stream>>>(x, n1g, n1b, ing, inb, xn);
  // 2) xz = xn @ in_w^T   [NT,512]
  gemm_k<DD,0><<<dim3(512/64, NT/64), 256, 0, stream>>>(xn, in_w, nullptr, nullptr, xz, 2*ED);
  // 3) uc = silu(causal_conv(u) + conv_b)
  conv_k<<<NT, 256, 0, stream>>>(xz, conv_w, conv_b, uc);
  // 4) dbc = uc @ xproj_w^T  [NT,40]
  xproj_k<<<NT/32, 256, 0, stream>>>(uc, xproj_w, dbc);
  // 5) delta = softplus(dt @ dt_w^T + dt_b)
  delta_k<<<NT, 256, 0, stream>>>(dbc, dt_w, dt_b, delta);
  // 6-8) chunked selective scan + gating -> y
  scan1_k<<<dim3(ED/16, NC, BB), 256, 0, stream>>>(delta, uc, dbc, A_log, cA, cH);
  scan2_k<<<(BB*NN*ED)/256, 256, 0, stream>>>(cA, cH, cP);
  scan3_k<<<dim3(ED/16, NC, BB), 256, 0, stream>>>(delta, uc, dbc, xz, A_log, Dpv, cP, y);
  // 9) xnew = y @ out_w^T + x
  gemm_k<ED,1><<<dim3(DD/64, NT/64), 256, 0, stream>>>(y, out_w, nullptr, x, xnew, DD);
  // 10) hln = norm1(xnew)
  ln_k<false><<<NT, 128, 0, stream>>>(xnew, n1g, n1b, nullptr, nullptr, hln);
  // 11) hmlp = gelu(hln @ fc1_w^T + fc1_b)
  gemm_k<DD,2><<<dim3(HH/64, NT/64), 256, 0, stream>>>(hln, fc1_w, fc1_b, nullptr, hmlp, HH);
  // 12) out = hmlp @ fc2_w^T + fc2_b + xnew
  gemm_k<HH,3><<<dim3(DD/64, NT/64), 256, 0, stream>>>(hmlp, fc2_w, fc2_b, xnew, out, DD);
}

// Round 2
// 264.772 us; speedup vs baseline: 1.1485x; 1.1485x over previous
//
#include <hip/hip_runtime.h>
#include <hip/hip_bf16.h>
#include <math.h>

// Problem constants (match reference)
#define BB 2
#define LL 4096
#define DD 128
#define ED 256
#define NN 16
#define KK 4
#define RR 8
#define HH 256
#define NT (BB*LL)          // 8192 tokens
#define NC 128              // chunks for scan
#define LC 32               // chunk length (NC*LC == LL)

// ---------------------------------------------------------------------------
// LayerNorm, wave-per-token (2 elems/lane, shuffle-only, no LDS/barrier).
// Block 256 = 4 waves = 4 tokens.
// ---------------------------------------------------------------------------
template<bool DOUBLE>
__global__ __launch_bounds__(256) void ln2_k(const float* __restrict__ x,
    const float* __restrict__ g1, const float* __restrict__ b1,
    const float* __restrict__ g2, const float* __restrict__ b2,
    float* __restrict__ out) {
  const int token = blockIdx.x*4 + (threadIdx.x >> 6);
  const int lane  = threadIdx.x & 63;
  float2 v = *(const float2*)(x + (size_t)token*DD + lane*2);

  auto wsum = [&](float s) -> float {
    s += __shfl_xor(s, 32); s += __shfl_xor(s, 16); s += __shfl_xor(s, 8);
    s += __shfl_xor(s, 4);  s += __shfl_xor(s, 2);  s += __shfl_xor(s, 1);
    return s;
  };

  float mean = wsum(v.x + v.y) * (1.f/128.f);
  float cx = v.x - mean, cy = v.y - mean;
  float var = wsum(cx*cx + cy*cy) * (1.f/128.f);
  float rs = rsqrtf(var + 1e-5f);
  const float2 g = *(const float2*)(g1 + lane*2);
  const float2 bb = *(const float2*)(b1 + lane*2);
  float yx = cx*rs*g.x + bb.x;
  float yy = cy*rs*g.y + bb.y;
  if constexpr (DOUBLE) {
    float m2 = wsum(yx + yy) * (1.f/128.f);
    float c2x = yx - m2, c2y = yy - m2;
    float v2 = wsum(c2x*c2x + c2y*c2y) * (1.f/128.f);
    float rs2 = rsqrtf(v2 + 1e-5f);
    const float2 g2v = *(const float2*)(g2 + lane*2);
    const float2 b2v = *(const float2*)(b2 + lane*2);
    yx = c2x*rs2*g2v.x + b2v.x;
    yy = c2y*rs2*g2v.y + b2v.y;
  }
  *(float2*)(out + (size_t)token*DD + lane*2) = make_float2(yx, yy);
}

// ---------------------------------------------------------------------------
// Tiled fp32 GEMM: C[M,Nn] = A[M,KD] @ Bw[Nn,KD]^T  (weights stored [out,in])
// 64x64 tile, BK=16, 256 threads, 4x4 micro-tile per thread.
// EPI: 0 = none; 1 = +res; 2 = gelu(+bias); 3 = +bias +res
// ---------------------------------------------------------------------------
template<int KD, int EPI>
__global__ __launch_bounds__(256) void gemm_k(const float* __restrict__ A,
    const float* __restrict__ Bw, const float* __restrict__ bias,
    const float* __restrict__ res, float* __restrict__ C, int Nn) {
  __shared__ float As[16][68];
  __shared__ float Bs[16][68];
  const int row0 = blockIdx.y * 64;
  const int col0 = blockIdx.x * 64;
  const int tid = threadIdx.x;
  const int lm  = tid >> 2;          // 0..63 row within tile (loading)
  const int lk4 = (tid & 3) * 4;     // k sub-offset (float4)
  const int tm  = (tid >> 4) * 4;    // 0..60
  const int tn  = (tid & 15) * 4;    // 0..60

  float acc[4][4] = {};

  for (int k0 = 0; k0 < KD; k0 += 16) {
    const float4 av = *(const float4*)(A  + (size_t)(row0 + lm)*KD + k0 + lk4);
    const float4 bv = *(const float4*)(Bw + (size_t)(col0 + lm)*KD + k0 + lk4);
    __syncthreads();
    As[lk4+0][lm] = av.x; As[lk4+1][lm] = av.y;
    As[lk4+2][lm] = av.z; As[lk4+3][lm] = av.w;
    Bs[lk4+0][lm] = bv.x; Bs[lk4+1][lm] = bv.y;
    Bs[lk4+2][lm] = bv.z; Bs[lk4+3][lm] = bv.w;
    __syncthreads();
    #pragma unroll
    for (int k = 0; k < 16; k++) {
      const float4 a = *(const float4*)&As[k][tm];
      const float4 b = *(const float4*)&Bs[k][tn];
      acc[0][0] += a.x*b.x; acc[0][1] += a.x*b.y; acc[0][2] += a.x*b.z; acc[0][3] += a.x*b.w;
      acc[1][0] += a.y*b.x; acc[1][1] += a.y*b.y; acc[1][2] += a.y*b.z; acc[1][3] += a.y*b.w;
      acc[2][0] += a.z*b.x; acc[2][1] += a.z*b.y; acc[2][2] += a.z*b.z; acc[2][3] += a.z*b.w;
      acc[3][0] += a.w*b.x; acc[3][1] += a.w*b.y; acc[3][2] += a.w*b.z; acc[3][3] += a.w*b.w;
    }
  }

  #pragma unroll
  for (int i = 0; i < 4; i++) {
    const int row = row0 + tm + i;
    const int col = col0 + tn;
    float4 v = make_float4(acc[i][0], acc[i][1], acc[i][2], acc[i][3]);
    if constexpr (EPI == 2 || EPI == 3) {
      const float4 bb4 = *(const float4*)(bias + col);
      v.x += bb4.x; v.y += bb4.y; v.z += bb4.z; v.w += bb4.w;
    }
    if constexpr (EPI == 2) {
      v.x = 0.5f*v.x*(1.f + erff(v.x*0.70710678118f));
      v.y = 0.5f*v.y*(1.f + erff(v.y*0.70710678118f));
      v.z = 0.5f*v.z*(1.f + erff(v.z*0.70710678118f));
      v.w = 0.5f*v.w*(1.f + erff(v.w*0.70710678118f));
    }
    const size_t o = (size_t)row*Nn + col;
    if constexpr (EPI == 1 || EPI == 3) {
      const float4 r4 = *(const float4*)(res + o);
      v.x += r4.x; v.y += r4.y; v.z += r4.z; v.w += r4.w;
    }
    *(float4*)(C + o) = v;
  }
}

// ---------------------------------------------------------------------------
// Causal depthwise conv (K=4) + bias + silu. u lives inside xz (stride 512,
// cols 0..255). Output uc [NT, ED].
// ---------------------------------------------------------------------------
__global__ __launch_bounds__(256) void conv_k(const float* __restrict__ xz,
    const float* __restrict__ cw, const float* __restrict__ cb,
    float* __restrict__ uc) {
  const int token = blockIdx.x;
  const int e = threadIdx.x;
  const int b = token >> 12;       // /4096
  const int l = token & 4095;
  const float4 w = *(const float4*)(cw + e*4);
  float acc = cb[e];
  const float wv[4] = {w.x, w.y, w.z, w.w};
  #pragma unroll
  for (int k = 0; k < 4; k++) {
    const int ls = l - 3 + k;
    if (ls >= 0) acc += xz[((size_t)(b*LL + ls))*(2*ED) + e] * wv[k];
  }
  uc[(size_t)token*ED + e] = acc / (1.f + __expf(-acc));   // silu
}

// ---------------------------------------------------------------------------
// x_proj: dbc[t, r] = sum_e uc[t,e] * w[r,e], r < 40. 32 tokens per block.
// ---------------------------------------------------------------------------
__global__ __launch_bounds__(256) void xproj_k(const float* __restrict__ uc,
    const float* __restrict__ w, float* __restrict__ dbc) {
  const int t0 = blockIdx.x * 32;
  __shared__ float su[32][ED];
  const float4* src = (const float4*)(uc + (size_t)t0*ED);
  float4* dst = (float4*)(&su[0][0]);
  #pragma unroll
  for (int i = 0; i < 8; i++) dst[threadIdx.x + i*256] = src[threadIdx.x + i*256];
  __syncthreads();
  #pragma unroll
  for (int i = 0; i < 5; i++) {
    const int o = threadIdx.x + i*256;   // 0..1279 = 32 tokens x 40 outputs
    const int tl = o / 40, r = o - tl*40;
    const float4* u4 = (const float4*)(&su[tl][0]);
    const float4* w4 = (const float4*)(w + (size_t)r*ED);
    float acc = 0.f;
    #pragma unroll 8
    for (int k = 0; k < ED/4; k++) {
      const float4 a = u4[k], b = w4[k];
      acc += a.x*b.x + a.y*b.y + a.z*b.z + a.w*b.w;
    }
    dbc[(size_t)(t0 + tl)*40 + r] = acc;
  }
}

// ---------------------------------------------------------------------------
// delta[t,e] = softplus(sum_r dt[t,r]*dt_w[e,r] + dt_b[e])
// ---------------------------------------------------------------------------
__global__ __launch_bounds__(256) void delta_k(const float* __restrict__ dbc,
    const float* __restrict__ dtw, const float* __restrict__ dtb,
    float* __restrict__ delta) {
  const int token = blockIdx.x;
  const int e = threadIdx.x;
  __shared__ float dt[RR];
  if (threadIdx.x < RR) dt[threadIdx.x] = dbc[(size_t)token*40 + threadIdx.x];
  __syncthreads();
  const float4 w0 = *(const float4*)(dtw + e*RR);
  const float4 w1 = *(const float4*)(dtw + e*RR + 4);
  float acc = dtb[e]
      + dt[0]*w0.x + dt[1]*w0.y + dt[2]*w0.z + dt[3]*w0.w
      + dt[4]*w1.x + dt[5]*w1.y + dt[6]*w1.z + dt[7]*w1.w;
  delta[(size_t)token*ED + e] = (acc > 20.f) ? acc : log1pf(expf(acc));
}

// ---------------------------------------------------------------------------
// Scan phase 1: per-chunk (prodA, h_end), channel-per-thread, h[8] in regs.
// Thread owns (b,c,e, n-half). prodA = exp(Aen * sum(delta)) -- one exp/chunk.
// grid (2, NC, BB) x 256 threads: e = bx*128 + (tid>>1), n0 = (tid&1)*8.
// chunk arrays layout: idx = ((c*BB+b)*ED + e)*NN + n
// ---------------------------------------------------------------------------
__global__ __launch_bounds__(256) void scan1_k(const float* __restrict__ delta,
    const float* __restrict__ uc, const float* __restrict__ dbc,
    const float* __restrict__ A_log, float* __restrict__ cA,
    float* __restrict__ cH) {
  const int c = blockIdx.y, b = blockIdx.z;
  const int e  = blockIdx.x*128 + (threadIdx.x >> 1);
  const int n0 = (threadIdx.x & 1) * 8;
  const float4 a0 = *(const float4*)(A_log + e*NN + n0);
  const float4 a1 = *(const float4*)(A_log + e*NN + n0 + 4);
  float Aen[8] = {-__expf(a0.x), -__expf(a0.y), -__expf(a0.z), -__expf(a0.w),
                  -__expf(a1.x), -__expf(a1.y), -__expf(a1.z), -__expf(a1.w)};
  float h[8] = {};
  float sumd = 0.f;
  const size_t tok0 = (size_t)b*LL + (size_t)c*LC;
  for (int i = 0; i < LC; i++) {
    const size_t t = tok0 + i;
    const float dv = delta[t*ED + e];
    const float uv = uc[t*ED + e];
    const float du = dv * uv;
    const float4 B0 = *(const float4*)(dbc + t*40 + RR + n0);
    const float4 B1 = *(const float4*)(dbc + t*40 + RR + n0 + 4);
    const float Bv[8] = {B0.x,B0.y,B0.z,B0.w,B1.x,B1.y,B1.z,B1.w};
    sumd += dv;
    #pragma unroll
    for (int j = 0; j < 8; j++) {
      const float dA = __expf(dv * Aen[j]);
      h[j] = dA*h[j] + Bv[j]*du;
    }
  }
  const size_t base = (((size_t)c*BB + b)*ED + e)*NN + n0;
  *(float4*)(cA + base)     = make_float4(__expf(sumd*Aen[0]), __expf(sumd*Aen[1]),
                                          __expf(sumd*Aen[2]), __expf(sumd*Aen[3]));
  *(float4*)(cA + base + 4) = make_float4(__expf(sumd*Aen[4]), __expf(sumd*Aen[5]),
                                          __expf(sumd*Aen[6]), __expf(sumd*Aen[7]));
  *(float4*)(cH + base)     = make_float4(h[0], h[1], h[2], h[3]);
  *(float4*)(cH + base + 4) = make_float4(h[4], h[5], h[6], h[7]);
}

// ---------------------------------------------------------------------------
// Scan phase 2: scan over NC chunk summaries, in-place prefix into cA.
// 8192 threads = (b,e,n); consecutive threads -> contiguous addresses.
// ---------------------------------------------------------------------------
__global__ __launch_bounds__(256) void scan2_k(float* __restrict__ cA,
    const float* __restrict__ cH) {
  const int gt = blockIdx.x*256 + threadIdx.x;   // [0, BB*ED*NN)
  const int b = gt >> 12;
  const size_t base = (size_t)b*ED*NN + (gt & 4095);
  float h = 0.f;
  for (int c = 0; c < NC; c++) {
    const size_t idx = (size_t)c*(BB*ED*NN) + base;
    const float a = cA[idx], hh = cH[idx];
    cA[idx] = h;               // prefix (carry-in for chunk c)
    h = a*h + hh;
  }
}

// ---------------------------------------------------------------------------
// Scan phase 3: replay with prefix, in-register n-reduction (+1 shuffle for
// the half-pair), fuse gating: y = (scan_y + u*Dp) * silu(z).
// NOTE: y aliases delta (same [t,e] element read-then-written by same wave).
// ---------------------------------------------------------------------------
__global__ __launch_bounds__(256) void scan3_k(const float* __restrict__ delta,
    const float* __restrict__ uc, const float* __restrict__ dbc,
    const float* __restrict__ xz, const float* __restrict__ A_log,
    const float* __restrict__ Dpv, const float* __restrict__ cP,
    float* __restrict__ y) {
  const int c = blockIdx.y, b = blockIdx.z;
  const int e    = blockIdx.x*128 + (threadIdx.x >> 1);
  const int half = threadIdx.x & 1;
  const int n0   = half * 8;
  const float4 a0 = *(const float4*)(A_log + e*NN + n0);
  const float4 a1 = *(const float4*)(A_log + e*NN + n0 + 4);
  float Aen[8] = {-__expf(a0.x), -__expf(a0.y), -__expf(a0.z), -__expf(a0.w),
                  -__expf(a1.x), -__expf(a1.y), -__expf(a1.z), -__expf(a1.w)};
  const float Dpe = Dpv[e];
  const size_t base = (((size_t)c*BB + b)*ED + e)*NN + n0;
  const float4 h0 = *(const float4*)(cP + base);
  const float4 h1 = *(const float4*)(cP + base + 4);
  float h[8] = {h0.x,h0.y,h0.z,h0.w,h1.x,h1.y,h1.z,h1.w};
  const size_t tok0 = (size_t)b*LL + (size_t)c*LC;
  for (int i = 0; i < LC; i++) {
    const size_t t = tok0 + i;
    const float dv = delta[t*ED + e];
    const float uv = uc[t*ED + e];
    const float du = dv * uv;
    const float4 B0 = *(const float4*)(dbc + t*40 + RR + n0);
    const float4 B1 = *(const float4*)(dbc + t*40 + RR + n0 + 4);
    const float4 C0 = *(const float4*)(dbc + t*40 + RR + NN + n0);
    const float4 C1 = *(const float4*)(dbc + t*40 + RR + NN + n0 + 4);
    const float Bv[8] = {B0.x,B0.y,B0.z,B0.w,B1.x,B1.y,B1.z,B1.w};
    const float Cv[8] = {C0.x,C0.y,C0.z,C0.w,C1.x,C1.y,C1.z,C1.w};
    float part = 0.f;
    #pragma unroll
    for (int j = 0; j < 8; j++) {
      const float dA = __expf(dv * Aen[j]);
      h[j] = dA*h[j] + Bv[j]*du;
      part += h[j]*Cv[j];
    }
    part += __shfl_xor(part, 1);       // combine the two n-halves
    if (half == 0) {
      const float zv = xz[t*(2*ED) + ED + e];
      const float g = zv / (1.f + __expf(-zv));   // silu(z)
      y[t*ED + e] = (part + uv*Dpe) * g;
    }
  }
}

// ---------------------------------------------------------------------------
extern "C" void kernel_launch(void* const* d_in, const int* in_sizes, int n_in,
                              void* d_out, int out_size, void* d_ws, size_t ws_size,
                              hipStream_t stream) {
  const float* x      = (const float*)d_in[0];
  const float* n1g    = (const float*)d_in[1];
  const float* n1b    = (const float*)d_in[2];
  const float* ing    = (const float*)d_in[3];
  const float* inb    = (const float*)d_in[4];
  const float* in_w   = (const float*)d_in[5];
  const float* conv_w = (const float*)d_in[6];
  const float* conv_b = (const float*)d_in[7];
  const float* xproj_w= (const float*)d_in[8];
  const float* dt_w   = (const float*)d_in[9];
  const float* dt_b   = (const float*)d_in[10];
  const float* A_log  = (const float*)d_in[11];
  const float* Dpv    = (const float*)d_in[12];
  const float* out_w  = (const float*)d_in[13];
  const float* fc1_w  = (const float*)d_in[14];
  const float* fc1_b  = (const float*)d_in[15];
  const float* fc2_w  = (const float*)d_in[16];
  const float* fc2_b  = (const float*)d_in[17];
  float* out = (float*)d_out;

  // Workspace layout (floats). Total ~45 MB.
  float* ws    = (float*)d_ws;
  float* xn    = ws;                         // [NT, DD]        1,048,576
  float* xz    = xn    + (size_t)NT*DD;      // [NT, 2*ED]      4,194,304
  float* uc    = xz    + (size_t)NT*2*ED;    // [NT, ED]        2,097,152
  float* dbc   = uc    + (size_t)NT*ED;      // [NT, 40]          327,680
  float* delta = dbc   + (size_t)NT*40;      // [NT, ED]        2,097,152
  float* cAP   = delta + (size_t)NT*ED;      // [NC,B,ED,N]     1,048,576
  float* cH    = cAP   + (size_t)NC*BB*ED*NN;//                 1,048,576
  // Aliases (lifetimes are disjoint):
  float* y     = delta;   // phase3 reads delta[t,e] then writes y[t,e] in the
                          // same wave-iteration (write instr after read) -> safe
  float* xnew  = xn;      // xn dead after in_proj GEMM
  float* hln   = uc;      // uc dead after phase 3
  float* hmlp  = delta;   // y (=delta) dead after out_proj GEMM

  // 1) xn = inner_ln(norm1(x))
  ln2_k<true><<<NT/4, 256, 0, stream>>>(x, n1g, n1b, ing, inb, xn);
  // 2) xz = xn @ in_w^T   [NT,512]
  gemm_k<DD,0><<<dim3(512/64, NT/64), 256, 0, stream>>>(xn, in_w, nullptr, nullptr, xz, 2*ED);
  // 3) uc = silu(causal_conv(u) + conv_b)
  conv_k<<<NT, 256, 0, stream>>>(xz, conv_w, conv_b, uc);
  // 4) dbc = uc @ xproj_w^T  [NT,40]
  xproj_k<<<NT/32, 256, 0, stream>>>(uc, xproj_w, dbc);
  // 5) delta = softplus(dt @ dt_w^T + dt_b)
  delta_k<<<NT, 256, 0, stream>>>(dbc, dt_w, dt_b, delta);
  // 6-8) chunked selective scan + gating -> y
  scan1_k<<<dim3(2, NC, BB), 256, 0, stream>>>(delta, uc, dbc, A_log, cAP, cH);
  scan2_k<<<(BB*ED*NN)/256, 256, 0, stream>>>(cAP, cH);
  scan3_k<<<dim3(2, NC, BB), 256, 0, stream>>>(delta, uc, dbc, xz, A_log, Dpv, cAP, y);
  // 9) xnew = y @ out_w^T + x
  gemm_k<ED,1><<<dim3(DD/64, NT/64), 256, 0, stream>>>(y, out_w, nullptr, x, xnew, DD);
  // 10) hln = norm1(xnew)
  ln2_k<false><<<NT/4, 256, 0, stream>>>(xnew, n1g, n1b, nullptr, nullptr, hln);
  // 11) hmlp = gelu(hln @ fc1_w^T + fc1_b)
  gemm_k<DD,2><<<dim3(HH/64, NT/64), 256, 0, stream>>>(hln, fc1_w, fc1_b, nullptr, hmlp, HH);
  // 12) out = hmlp @ fc2_w^T + fc2_b + xnew
  gemm_k<HH,3><<<dim3(DD/64, NT/64), 256, 0, stream>>>(hmlp, fc2_w, fc2_b, xnew, out, DD);
}

// Round 3
// 237.776 us; speedup vs baseline: 1.2789x; 1.1135x over previous
//
#include <hip/hip_runtime.h>
#include <hip/hip_bf16.h>
#include <math.h>

// Problem constants (match reference)
#define BB 2
#define LL 4096
#define DD 128
#define ED 256
#define NN 16
#define KK 4
#define RR 8
#define HH 256
#define NT (BB*LL)          // 8192 tokens
#define NC 128              // chunks for scan
#define LC 32               // chunk length (NC*LC == LL)

typedef __attribute__((ext_vector_type(8))) short short8;
typedef __attribute__((ext_vector_type(8))) unsigned short ushort8v;
typedef __attribute__((ext_vector_type(4))) float floatx4;

__device__ __forceinline__ unsigned short f2bf(float f) {
  unsigned int b = __builtin_bit_cast(unsigned int, f);
  b += 0x7FFFu + ((b >> 16) & 1u);           // round-to-nearest-even
  return (unsigned short)(b >> 16);
}

// ---------------------------------------------------------------------------
// LayerNorm, wave-per-token (2 elems/lane, shuffle-only, no LDS/barrier).
// ---------------------------------------------------------------------------
template<bool DOUBLE>
__global__ __launch_bounds__(256) void ln2_k(const float* __restrict__ x,
    const float* __restrict__ g1, const float* __restrict__ b1,
    const float* __restrict__ g2, const float* __restrict__ b2,
    float* __restrict__ out) {
  const int token = blockIdx.x*4 + (threadIdx.x >> 6);
  const int lane  = threadIdx.x & 63;
  float2 v = *(const float2*)(x + (size_t)token*DD + lane*2);

  auto wsum = [&](float s) -> float {
    s += __shfl_xor(s, 32); s += __shfl_xor(s, 16); s += __shfl_xor(s, 8);
    s += __shfl_xor(s, 4);  s += __shfl_xor(s, 2);  s += __shfl_xor(s, 1);
    return s;
  };

  float mean = wsum(v.x + v.y) * (1.f/128.f);
  float cx = v.x - mean, cy = v.y - mean;
  float var = wsum(cx*cx + cy*cy) * (1.f/128.f);
  float rs = rsqrtf(var + 1e-5f);
  const float2 g = *(const float2*)(g1 + lane*2);
  const float2 bb = *(const float2*)(b1 + lane*2);
  float yx = cx*rs*g.x + bb.x;
  float yy = cy*rs*g.y + bb.y;
  if constexpr (DOUBLE) {
    float m2 = wsum(yx + yy) * (1.f/128.f);
    float c2x = yx - m2, c2y = yy - m2;
    float v2 = wsum(c2x*c2x + c2y*c2y) * (1.f/128.f);
    float rs2 = rsqrtf(v2 + 1e-5f);
    const float2 g2v = *(const float2*)(g2 + lane*2);
    const float2 b2v = *(const float2*)(b2 + lane*2);
    yx = c2x*rs2*g2v.x + b2v.x;
    yy = c2y*rs2*g2v.y + b2v.y;
  }
  *(float2*)(out + (size_t)token*DD + lane*2) = make_float2(yx, yy);
}

// ---------------------------------------------------------------------------
// bf16 MFMA GEMM: C[M,Nn] = A[M,KD] @ W[Nn,KD]^T, fp32 in/out, bf16 compute.
// 64x64 tile, 4 waves (2x2), each wave 32x32 = 2x2 fragments of 16x16x32.
// fp32->bf16 conversion happens in the LDS staging path.
// EPI: 0 = none; 1 = +res; 2 = gelu(+bias); 3 = +bias +res
// ---------------------------------------------------------------------------
template<int KD, int EPI>
__global__ __launch_bounds__(256) void gemm_bf_k(const float* __restrict__ A,
    const float* __restrict__ W, const float* __restrict__ bias,
    const float* __restrict__ res, float* __restrict__ C, int Nn) {
  static_assert(KD % 128 == 0, "KD multiple of 128");
  __shared__ unsigned short As[64][136];   // 64 rows x 128 bf16, pad 8
  __shared__ unsigned short Ws[64][136];

  const int row0 = blockIdx.y * 64;
  const int col0 = blockIdx.x * 64;
  const int tid  = threadIdx.x;
  const int wave = tid >> 6;
  const int lane = tid & 63;
  const int quad = lane >> 4;
  const int l16  = lane & 15;
  const int wm = (wave & 1) * 32;
  const int wn = (wave >> 1) * 32;
  const int lr = tid >> 2;            // staging row 0..63
  const int lk = (tid & 3) * 32;      // staging k-offset (32 floats)

  floatx4 acc[2][2] = {};

  for (int ks0 = 0; ks0 < KD; ks0 += 128) {
    const float* Ap = A + (size_t)(row0 + lr)*KD + ks0 + lk;
    const float* Wp = W + (size_t)(col0 + lr)*KD + ks0 + lk;
    float4 av[8], wv[8];
    #pragma unroll
    for (int g = 0; g < 8; g++) {
      av[g] = *(const float4*)(Ap + g*4);
      wv[g] = *(const float4*)(Wp + g*4);
    }
    __syncthreads();
    #pragma unroll
    for (int g = 0; g < 4; g++) {
      ushort8v pa, pw;
      pa[0]=f2bf(av[2*g].x);   pa[1]=f2bf(av[2*g].y);
      pa[2]=f2bf(av[2*g].z);   pa[3]=f2bf(av[2*g].w);
      pa[4]=f2bf(av[2*g+1].x); pa[5]=f2bf(av[2*g+1].y);
      pa[6]=f2bf(av[2*g+1].z); pa[7]=f2bf(av[2*g+1].w);
      pw[0]=f2bf(wv[2*g].x);   pw[1]=f2bf(wv[2*g].y);
      pw[2]=f2bf(wv[2*g].z);   pw[3]=f2bf(wv[2*g].w);
      pw[4]=f2bf(wv[2*g+1].x); pw[5]=f2bf(wv[2*g+1].y);
      pw[6]=f2bf(wv[2*g+1].z); pw[7]=f2bf(wv[2*g+1].w);
      *(ushort8v*)&As[lr][lk + g*8] = pa;
      *(ushort8v*)&Ws[lr][lk + g*8] = pw;
    }
    __syncthreads();
    #pragma unroll
    for (int ks = 0; ks < 4; ks++) {
      const int ko = ks*32 + quad*8;
      short8 a0 = *(const short8*)&As[wm +      l16][ko];
      short8 a1 = *(const short8*)&As[wm + 16 + l16][ko];
      short8 b0 = *(const short8*)&Ws[wn +      l16][ko];
      short8 b1 = *(const short8*)&Ws[wn + 16 + l16][ko];
      acc[0][0] = __builtin_amdgcn_mfma_f32_16x16x32_bf16(a0, b0, acc[0][0], 0, 0, 0);
      acc[0][1] = __builtin_amdgcn_mfma_f32_16x16x32_bf16(a0, b1, acc[0][1], 0, 0, 0);
      acc[1][0] = __builtin_amdgcn_mfma_f32_16x16x32_bf16(a1, b0, acc[1][0], 0, 0, 0);
      acc[1][1] = __builtin_amdgcn_mfma_f32_16x16x32_bf16(a1, b1, acc[1][1], 0, 0, 0);
    }
  }

  #pragma unroll
  for (int i = 0; i < 2; i++) {
    #pragma unroll
    for (int j = 0; j < 2; j++) {
      const int n = col0 + wn + j*16 + l16;
      float bn = 0.f;
      if constexpr (EPI == 2 || EPI == 3) bn = bias[n];
      #pragma unroll
      for (int r = 0; r < 4; r++) {
        const int m = row0 + wm + i*16 + quad*4 + r;
        float v = acc[i][j][r];
        if constexpr (EPI == 2 || EPI == 3) v += bn;
        if constexpr (EPI == 2) v = 0.5f*v*(1.f + erff(v*0.70710678118f));
        const size_t o = (size_t)m*Nn + n;
        if constexpr (EPI == 1 || EPI == 3) v += res[o];
        C[o] = v;
      }
    }
  }
}

// ---------------------------------------------------------------------------
// Fused conv(K=4,causal)+bias+silu -> x_proj -> delta. 32 tokens per block.
// Writes uc [NT,ED], dbc [NT,40], delta [NT,ED].
// ---------------------------------------------------------------------------
__global__ __launch_bounds__(256) void cxd_k(const float* __restrict__ xz,
    const float* __restrict__ cw, const float* __restrict__ cb,
    const float* __restrict__ xpw, const float* __restrict__ dtw,
    const float* __restrict__ dtb, float* __restrict__ uc,
    float* __restrict__ dbc, float* __restrict__ delta) {
  __shared__ float su[32][ED];     // conv output tile
  __shared__ float sd[32][48];     // dt part of dbc (only cols 0..7 used later)
  const int t0 = blockIdx.x * 32;  // never crosses batch boundary (4096%32==0)
  const int l0 = t0 & 4095;
  const int e  = threadIdx.x;

  const float4 w = *(const float4*)(cw + e*4);
  const float cbe = cb[e];
  float h0 = 0.f, h1 = 0.f, h2 = 0.f;
  if (l0) {
    h0 = xz[(size_t)(t0-3)*(2*ED) + e];
    h1 = xz[(size_t)(t0-2)*(2*ED) + e];
    h2 = xz[(size_t)(t0-1)*(2*ED) + e];
  }
  #pragma unroll 4
  for (int i = 0; i < 32; i++) {
    const float cur = xz[(size_t)(t0+i)*(2*ED) + e];
    const float a = cbe + h0*w.x + h1*w.y + h2*w.z + cur*w.w;
    const float s = a / (1.f + __expf(-a));
    su[i][e] = s;
    uc[(size_t)(t0+i)*ED + e] = s;
    h0 = h1; h1 = h2; h2 = cur;
  }
  __syncthreads();

  // x_proj: 32 tokens x 40 outputs = 1280 dots of length 256
  #pragma unroll
  for (int i = 0; i < 5; i++) {
    const int o = threadIdx.x + i*256;
    const int tl = o / 40, r = o - tl*40;
    const float4* u4 = (const float4*)(&su[tl][0]);
    const float4* w4 = (const float4*)(xpw + (size_t)r*ED);
    float acc = 0.f;
    #pragma unroll 8
    for (int k = 0; k < ED/4; k++) {
      const float4 a = u4[k], b = w4[k];
      acc += a.x*b.x + a.y*b.y + a.z*b.z + a.w*b.w;
    }
    if (r < RR) sd[tl][r] = acc;
    dbc[(size_t)(t0 + tl)*40 + r] = acc;
  }
  __syncthreads();

  // delta: softplus(dt @ dt_w^T + dt_b)
  const float4 w0 = *(const float4*)(dtw + e*RR);
  const float4 w1 = *(const float4*)(dtw + e*RR + 4);
  const float db = dtb[e];
  for (int tl = 0; tl < 32; tl++) {
    const float acc = db
        + sd[tl][0]*w0.x + sd[tl][1]*w0.y + sd[tl][2]*w0.z + sd[tl][3]*w0.w
        + sd[tl][4]*w1.x + sd[tl][5]*w1.y + sd[tl][6]*w1.z + sd[tl][7]*w1.w;
    delta[(size_t)(t0+tl)*ED + e] = (acc > 20.f) ? acc : log1pf(__expf(acc));
  }
}

// ---------------------------------------------------------------------------
// Scan phase 1: per-chunk (prodA, h_end), channel-per-thread, h[8] in regs.
// ---------------------------------------------------------------------------
__global__ __launch_bounds__(256) void scan1_k(const float* __restrict__ delta,
    const float* __restrict__ uc, const float* __restrict__ dbc,
    const float* __restrict__ A_log, float* __restrict__ cA,
    float* __restrict__ cH) {
  const int c = blockIdx.y, b = blockIdx.z;
  const int e  = blockIdx.x*128 + (threadIdx.x >> 1);
  const int n0 = (threadIdx.x & 1) * 8;
  const float4 a0 = *(const float4*)(A_log + e*NN + n0);
  const float4 a1 = *(const float4*)(A_log + e*NN + n0 + 4);
  float Aen[8] = {-__expf(a0.x), -__expf(a0.y), -__expf(a0.z), -__expf(a0.w),
                  -__expf(a1.x), -__expf(a1.y), -__expf(a1.z), -__expf(a1.w)};
  float h[8] = {};
  float sumd = 0.f;
  const size_t tok0 = (size_t)b*LL + (size_t)c*LC;
  for (int i = 0; i < LC; i++) {
    const size_t t = tok0 + i;
    const float dv = delta[t*ED + e];
    const float uv = uc[t*ED + e];
    const float du = dv * uv;
    const float4 B0 = *(const float4*)(dbc + t*40 + RR + n0);
    const float4 B1 = *(const float4*)(dbc + t*40 + RR + n0 + 4);
    const float Bv[8] = {B0.x,B0.y,B0.z,B0.w,B1.x,B1.y,B1.z,B1.w};
    sumd += dv;
    #pragma unroll
    for (int j = 0; j < 8; j++) {
      const float dA = __expf(dv * Aen[j]);
      h[j] = dA*h[j] + Bv[j]*du;
    }
  }
  const size_t base = (((size_t)c*BB + b)*ED + e)*NN + n0;
  *(float4*)(cA + base)     = make_float4(__expf(sumd*Aen[0]), __expf(sumd*Aen[1]),
                                          __expf(sumd*Aen[2]), __expf(sumd*Aen[3]));
  *(float4*)(cA + base + 4) = make_float4(__expf(sumd*Aen[4]), __expf(sumd*Aen[5]),
                                          __expf(sumd*Aen[6]), __expf(sumd*Aen[7]));
  *(float4*)(cH + base)     = make_float4(h[0], h[1], h[2], h[3]);
  *(float4*)(cH + base + 4) = make_float4(h[4], h[5], h[6], h[7]);
}

// ---------------------------------------------------------------------------
// Scan phase 2: scan over NC chunk summaries, in-place prefix into cA.
// ---------------------------------------------------------------------------
__global__ __launch_bounds__(256) void scan2_k(float* __restrict__ cA,
    const float* __restrict__ cH) {
  const int gt = blockIdx.x*256 + threadIdx.x;   // [0, BB*ED*NN)
  const int b = gt >> 12;
  const size_t base = (size_t)b*ED*NN + (gt & 4095);
  float h = 0.f;
  for (int c = 0; c < NC; c++) {
    const size_t idx = (size_t)c*(BB*ED*NN) + base;
    const float a = cA[idx], hh = cH[idx];
    cA[idx] = h;               // prefix (carry-in for chunk c)
    h = a*h + hh;
  }
}

// ---------------------------------------------------------------------------
// Scan phase 3: replay with prefix, in-register n-reduction (+1 shuffle),
// fused gating: y = (scan_y + u*Dp) * silu(z).  y aliases delta (safe).
// ---------------------------------------------------------------------------
__global__ __launch_bounds__(256) void scan3_k(const float* __restrict__ delta,
    const float* __restrict__ uc, const float* __restrict__ dbc,
    const float* __restrict__ xz, const float* __restrict__ A_log,
    const float* __restrict__ Dpv, const float* __restrict__ cP,
    float* __restrict__ y) {
  const int c = blockIdx.y, b = blockIdx.z;
  const int e    = blockIdx.x*128 + (threadIdx.x >> 1);
  const int half = threadIdx.x & 1;
  const int n0   = half * 8;
  const float4 a0 = *(const float4*)(A_log + e*NN + n0);
  const float4 a1 = *(const float4*)(A_log + e*NN + n0 + 4);
  float Aen[8] = {-__expf(a0.x), -__expf(a0.y), -__expf(a0.z), -__expf(a0.w),
                  -__expf(a1.x), -__expf(a1.y), -__expf(a1.z), -__expf(a1.w)};
  const float Dpe = Dpv[e];
  const size_t base = (((size_t)c*BB + b)*ED + e)*NN + n0;
  const float4 h0 = *(const float4*)(cP + base);
  const float4 h1 = *(const float4*)(cP + base + 4);
  float h[8] = {h0.x,h0.y,h0.z,h0.w,h1.x,h1.y,h1.z,h1.w};
  const size_t tok0 = (size_t)b*LL + (size_t)c*LC;
  for (int i = 0; i < LC; i++) {
    const size_t t = tok0 + i;
    const float dv = delta[t*ED + e];
    const float uv = uc[t*ED + e];
    const float du = dv * uv;
    const float4 B0 = *(const float4*)(dbc + t*40 + RR + n0);
    const float4 B1 = *(const float4*)(dbc + t*40 + RR + n0 + 4);
    const float4 C0 = *(const float4*)(dbc + t*40 + RR + NN + n0);
    const float4 C1 = *(const float4*)(dbc + t*40 + RR + NN + n0 + 4);
    const float Bv[8] = {B0.x,B0.y,B0.z,B0.w,B1.x,B1.y,B1.z,B1.w};
    const float Cv[8] = {C0.x,C0.y,C0.z,C0.w,C1.x,C1.y,C1.z,C1.w};
    float part = 0.f;
    #pragma unroll
    for (int j = 0; j < 8; j++) {
      const float dA = __expf(dv * Aen[j]);
      h[j] = dA*h[j] + Bv[j]*du;
      part += h[j]*Cv[j];
    }
    part += __shfl_xor(part, 1);       // combine the two n-halves
    if (half == 0) {
      const float zv = xz[t*(2*ED) + ED + e];
      const float g = zv / (1.f + __expf(-zv));   // silu(z)
      y[t*ED + e] = (part + uv*Dpe) * g;
    }
  }
}

// ---------------------------------------------------------------------------
extern "C" void kernel_launch(void* const* d_in, const int* in_sizes, int n_in,
                              void* d_out, int out_size, void* d_ws, size_t ws_size,
                              hipStream_t stream) {
  const float* x      = (const float*)d_in[0];
  const float* n1g    = (const float*)d_in[1];
  const float* n1b    = (const float*)d_in[2];
  const float* ing    = (const float*)d_in[3];
  const float* inb    = (const float*)d_in[4];
  const float* in_w   = (const float*)d_in[5];
  const float* conv_w = (const float*)d_in[6];
  const float* conv_b = (const float*)d_in[7];
  const float* xproj_w= (const float*)d_in[8];
  const float* dt_w   = (const float*)d_in[9];
  const float* dt_b   = (const float*)d_in[10];
  const float* A_log  = (const float*)d_in[11];
  const float* Dpv    = (const float*)d_in[12];
  const float* out_w  = (const float*)d_in[13];
  const float* fc1_w  = (const float*)d_in[14];
  const float* fc1_b  = (const float*)d_in[15];
  const float* fc2_w  = (const float*)d_in[16];
  const float* fc2_b  = (const float*)d_in[17];
  float* out = (float*)d_out;

  // Workspace layout (floats). Total ~45 MB.
  float* ws    = (float*)d_ws;
  float* xn    = ws;                         // [NT, DD]
  float* xz    = xn    + (size_t)NT*DD;      // [NT, 2*ED]
  float* uc    = xz    + (size_t)NT*2*ED;    // [NT, ED]
  float* dbc   = uc    + (size_t)NT*ED;      // [NT, 40]
  float* delta = dbc   + (size_t)NT*40;      // [NT, ED]
  float* cAP   = delta + (size_t)NT*ED;      // [NC,B,ED,N]
  float* cH    = cAP   + (size_t)NC*BB*ED*NN;
  // Aliases (lifetimes are disjoint):
  float* y     = delta;   // scan3 reads delta[t,e] then writes y[t,e] same iter
  float* xnew  = xn;      // xn dead after in_proj GEMM
  float* hln   = uc;      // uc dead after scan3
  float* hmlp  = delta;   // y (=delta) dead after out_proj GEMM

  // 1) xn = inner_ln(norm1(x))
  ln2_k<true><<<NT/4, 256, 0, stream>>>(x, n1g, n1b, ing, inb, xn);
  // 2) xz = xn @ in_w^T   [NT,512]   (bf16 MFMA)
  gemm_bf_k<DD,0><<<dim3(512/64, NT/64), 256, 0, stream>>>(xn, in_w, nullptr, nullptr, xz, 2*ED);
  // 3) fused conv+silu, x_proj, delta
  cxd_k<<<NT/32, 256, 0, stream>>>(xz, conv_w, conv_b, xproj_w, dt_w, dt_b, uc, dbc, delta);
  // 4-6) chunked selective scan + gating -> y
  scan1_k<<<dim3(2, NC, BB), 256, 0, stream>>>(delta, uc, dbc, A_log, cAP, cH);
  scan2_k<<<(BB*ED*NN)/256, 256, 0, stream>>>(cAP, cH);
  scan3_k<<<dim3(2, NC, BB), 256, 0, stream>>>(delta, uc, dbc, xz, A_log, Dpv, cAP, y);
  // 7) xnew = y @ out_w^T + x   (bf16 MFMA)
  gemm_bf_k<ED,1><<<dim3(DD/64, NT/64), 256, 0, stream>>>(y, out_w, nullptr, x, xnew, DD);
  // 8) hln = norm1(xnew)
  ln2_k<false><<<NT/4, 256, 0, stream>>>(xnew, n1g, n1b, nullptr, nullptr, hln);
  // 9) hmlp = gelu(hln @ fc1_w^T + fc1_b)   (bf16 MFMA)
  gemm_bf_k<DD,2><<<dim3(HH/64, NT/64), 256, 0, stream>>>(hln, fc1_w, fc1_b, nullptr, hmlp, HH);
  // 10) out = hmlp @ fc2_w^T + fc2_b + xnew   (bf16 MFMA)
  gemm_bf_k<HH,3><<<dim3(DD/64, NT/64), 256, 0, stream>>>(hmlp, fc2_w, fc2_b, xnew, out, DD);
}

// Round 4
// 216.640 us; speedup vs baseline: 1.4037x; 1.0976x over previous
//
#include <hip/hip_runtime.h>
#include <hip/hip_bf16.h>
#include <math.h>

// Problem constants (match reference)
#define BB 2
#define LL 4096
#define DD 128
#define ED 256
#define NN 16
#define KK 4
#define RR 8
#define HH 256
#define NT (BB*LL)          // 8192 tokens
#define NC 128              // chunks for scan
#define LC 32               // chunk length (NC*LC == LL)

typedef __attribute__((ext_vector_type(8))) short short8;
typedef __attribute__((ext_vector_type(8))) unsigned short ushort8v;
typedef __attribute__((ext_vector_type(4))) float floatx4;

__device__ __forceinline__ unsigned short f2bf(float f) {
  unsigned int b = __builtin_bit_cast(unsigned int, f);
  b += 0x7FFFu + ((b >> 16) & 1u);           // round-to-nearest-even
  return (unsigned short)(b >> 16);
}

// ---------------------------------------------------------------------------
// One-shot fp32->bf16 conversion of the 4 GEMM weight matrices.
// in_w 65536, out_w 32768, fc1_w 32768, fc2_w 32768 floats (float4 units:
// 16384 / 8192 / 8192 / 8192, total 40960).
// ---------------------------------------------------------------------------
__global__ __launch_bounds__(256) void cvt4_k(const float* __restrict__ a,
    const float* __restrict__ b, const float* __restrict__ c,
    const float* __restrict__ d, unsigned short* __restrict__ oa,
    unsigned short* __restrict__ ob, unsigned short* __restrict__ oc,
    unsigned short* __restrict__ od) {
  const int i = blockIdx.x*256 + threadIdx.x;   // < 40960 float4s
  const float* src; unsigned short* dst; int off;
  if (i < 16384)      { src = a; dst = oa; off = i; }
  else if (i < 24576) { src = b; dst = ob; off = i - 16384; }
  else if (i < 32768) { src = c; dst = oc; off = i - 24576; }
  else                { src = d; dst = od; off = i - 32768; }
  const float4 v = ((const float4*)src)[off];
  unsigned int lo = f2bf(v.x) | ((unsigned int)f2bf(v.y) << 16);
  unsigned int hi = f2bf(v.z) | ((unsigned int)f2bf(v.w) << 16);
  ((uint2*)dst)[off] = make_uint2(lo, hi);
}

// ---------------------------------------------------------------------------
// LayerNorm, wave-per-token, bf16 output (feeds GEMM A-operand only).
// ---------------------------------------------------------------------------
template<bool DOUBLE>
__global__ __launch_bounds__(256) void ln2_k(const float* __restrict__ x,
    const float* __restrict__ g1, const float* __restrict__ b1,
    const float* __restrict__ g2, const float* __restrict__ b2,
    unsigned short* __restrict__ out) {
  const int token = blockIdx.x*4 + (threadIdx.x >> 6);
  const int lane  = threadIdx.x & 63;
  float2 v = *(const float2*)(x + (size_t)token*DD + lane*2);

  auto wsum = [&](float s) -> float {
    s += __shfl_xor(s, 32); s += __shfl_xor(s, 16); s += __shfl_xor(s, 8);
    s += __shfl_xor(s, 4);  s += __shfl_xor(s, 2);  s += __shfl_xor(s, 1);
    return s;
  };

  float mean = wsum(v.x + v.y) * (1.f/128.f);
  float cx = v.x - mean, cy = v.y - mean;
  float var = wsum(cx*cx + cy*cy) * (1.f/128.f);
  float rs = rsqrtf(var + 1e-5f);
  const float2 g = *(const float2*)(g1 + lane*2);
  const float2 bb = *(const float2*)(b1 + lane*2);
  float yx = cx*rs*g.x + bb.x;
  float yy = cy*rs*g.y + bb.y;
  if constexpr (DOUBLE) {
    float m2 = wsum(yx + yy) * (1.f/128.f);
    float c2x = yx - m2, c2y = yy - m2;
    float v2 = wsum(c2x*c2x + c2y*c2y) * (1.f/128.f);
    float rs2 = rsqrtf(v2 + 1e-5f);
    const float2 g2v = *(const float2*)(g2 + lane*2);
    const float2 b2v = *(const float2*)(b2 + lane*2);
    yx = c2x*rs2*g2v.x + b2v.x;
    yy = c2y*rs2*g2v.y + b2v.y;
  }
  const unsigned int packed = f2bf(yx) | ((unsigned int)f2bf(yy) << 16);
  *(unsigned int*)(out + (size_t)token*DD + lane*2) = packed;
}

// ---------------------------------------------------------------------------
// bf16 MFMA GEMM: C[M,Nn] = A[M,KD] @ W[Nn,KD]^T; A,W pre-converted bf16.
// 64x64 tile, 4 waves (2x2 of 32x32), 16x16x32 fragments. No staging ALU.
// EPI: 0 = none; 1 = +res; 2 = gelu(+bias); 3 = +bias +res
// OT: float or unsigned short (bf16 out)
// ---------------------------------------------------------------------------
template<int KD, int EPI, typename OT>
__global__ __launch_bounds__(256) void gemm_bf_k(
    const unsigned short* __restrict__ A, const unsigned short* __restrict__ W,
    const float* __restrict__ bias, const float* __restrict__ res,
    OT* __restrict__ C, int Nn) {
  static_assert(KD % 128 == 0, "KD multiple of 128");
  __shared__ unsigned short As[64][136];   // 64 rows x 128 bf16, pad 8
  __shared__ unsigned short Ws[64][136];

  const int row0 = blockIdx.y * 64;
  const int col0 = blockIdx.x * 64;
  const int tid  = threadIdx.x;
  const int wave = tid >> 6;
  const int lane = tid & 63;
  const int quad = lane >> 4;
  const int l16  = lane & 15;
  const int wm = (wave & 1) * 32;
  const int wn = (wave >> 1) * 32;
  const int lr = tid >> 2;            // staging row 0..63
  const int lc = (tid & 3) * 32;      // staging col (32 bf16 = 64 B)

  floatx4 acc[2][2] = {};

  for (int ks0 = 0; ks0 < KD; ks0 += 128) {
    const unsigned short* Ap = A + (size_t)(row0 + lr)*KD + ks0 + lc;
    const unsigned short* Wp = W + (size_t)(col0 + lr)*KD + ks0 + lc;
    ushort8v av[4], wv[4];
    #pragma unroll
    for (int g = 0; g < 4; g++) {
      av[g] = *(const ushort8v*)(Ap + g*8);
      wv[g] = *(const ushort8v*)(Wp + g*8);
    }
    __syncthreads();
    #pragma unroll
    for (int g = 0; g < 4; g++) {
      *(ushort8v*)&As[lr][lc + g*8] = av[g];
      *(ushort8v*)&Ws[lr][lc + g*8] = wv[g];
    }
    __syncthreads();
    #pragma unroll
    for (int ks = 0; ks < 4; ks++) {
      const int ko = ks*32 + quad*8;
      short8 a0 = *(const short8*)&As[wm +      l16][ko];
      short8 a1 = *(const short8*)&As[wm + 16 + l16][ko];
      short8 b0 = *(const short8*)&Ws[wn +      l16][ko];
      short8 b1 = *(const short8*)&Ws[wn + 16 + l16][ko];
      acc[0][0] = __builtin_amdgcn_mfma_f32_16x16x32_bf16(a0, b0, acc[0][0], 0, 0, 0);
      acc[0][1] = __builtin_amdgcn_mfma_f32_16x16x32_bf16(a0, b1, acc[0][1], 0, 0, 0);
      acc[1][0] = __builtin_amdgcn_mfma_f32_16x16x32_bf16(a1, b0, acc[1][0], 0, 0, 0);
      acc[1][1] = __builtin_amdgcn_mfma_f32_16x16x32_bf16(a1, b1, acc[1][1], 0, 0, 0);
    }
  }

  #pragma unroll
  for (int i = 0; i < 2; i++) {
    #pragma unroll
    for (int j = 0; j < 2; j++) {
      const int n = col0 + wn + j*16 + l16;
      float bn = 0.f;
      if constexpr (EPI == 2 || EPI == 3) bn = bias[n];
      #pragma unroll
      for (int r = 0; r < 4; r++) {
        const int m = row0 + wm + i*16 + quad*4 + r;
        float v = acc[i][j][r];
        if constexpr (EPI == 2 || EPI == 3) v += bn;
        if constexpr (EPI == 2) v = 0.5f*v*(1.f + erff(v*0.70710678118f));
        const size_t o = (size_t)m*Nn + n;
        if constexpr (EPI == 1 || EPI == 3) v += res[o];
        if constexpr (sizeof(OT) == 2) C[o] = (OT)f2bf(v);
        else                           C[o] = v;
      }
    }
  }
}

// ---------------------------------------------------------------------------
// Fused conv(K=4,causal)+bias+silu -> x_proj -> delta. 16 tokens per block
// (512 blocks -> 2 blocks/CU). Writes uc [NT,ED], dbc [NT,40], delta [NT,ED].
// ---------------------------------------------------------------------------
__global__ __launch_bounds__(256) void cxd2_k(const float* __restrict__ xz,
    const float* __restrict__ cw, const float* __restrict__ cb,
    const float* __restrict__ xpw, const float* __restrict__ dtw,
    const float* __restrict__ dtb, float* __restrict__ uc,
    float* __restrict__ dbc, float* __restrict__ delta) {
  __shared__ float su[16][ED];     // conv output tile (16 KB)
  __shared__ float sd[16][8];      // dt part of dbc
  const int t0 = blockIdx.x * 16;  // never crosses batch (4096 % 16 == 0)
  const int l0 = t0 & 4095;
  const int e  = threadIdx.x;

  // conv: rolling window, one channel per thread
  const float4 w = *(const float4*)(cw + e*4);
  const float cbe = cb[e];
  float h0 = 0.f, h1 = 0.f, h2 = 0.f;
  if (l0) {
    h0 = xz[(size_t)(t0-3)*(2*ED) + e];
    h1 = xz[(size_t)(t0-2)*(2*ED) + e];
    h2 = xz[(size_t)(t0-1)*(2*ED) + e];
  }
  #pragma unroll 4
  for (int i = 0; i < 16; i++) {
    const float cur = xz[(size_t)(t0+i)*(2*ED) + e];
    const float a = cbe + h0*w.x + h1*w.y + h2*w.z + cur*w.w;
    const float s = a / (1.f + __expf(-a));
    su[i][e] = s;
    uc[(size_t)(t0+i)*ED + e] = s;
    h0 = h1; h1 = h2; h2 = cur;
  }
  __syncthreads();

  // x_proj: 16 tokens x 40 outputs = 640 dots of length 256
  #pragma unroll
  for (int p = 0; p < 3; p++) {
    const int o = p*256 + threadIdx.x;
    if (o < 640) {
      const int tl = o / 40, r = o - tl*40;
      const float4* u4 = (const float4*)(&su[tl][0]);
      const float4* w4 = (const float4*)(xpw + (size_t)r*ED);
      float acc = 0.f;
      #pragma unroll 8
      for (int k = 0; k < ED/4; k++) {
        const float4 a = u4[k], b = w4[k];
        acc += a.x*b.x + a.y*b.y + a.z*b.z + a.w*b.w;
      }
      if (r < RR) sd[tl][r] = acc;
      dbc[(size_t)(t0 + tl)*40 + r] = acc;
    }
  }
  __syncthreads();

  // delta: softplus(dt @ dt_w^T + dt_b), one channel per thread
  const float4 w0 = *(const float4*)(dtw + e*RR);
  const float4 w1 = *(const float4*)(dtw + e*RR + 4);
  const float db = dtb[e];
  #pragma unroll 4
  for (int tl = 0; tl < 16; tl++) {
    const float acc = db
        + sd[tl][0]*w0.x + sd[tl][1]*w0.y + sd[tl][2]*w0.z + sd[tl][3]*w0.w
        + sd[tl][4]*w1.x + sd[tl][5]*w1.y + sd[tl][6]*w1.z + sd[tl][7]*w1.w;
    delta[(size_t)(t0+tl)*ED + e] = (acc > 20.f) ? acc : log1pf(__expf(acc));
  }
}

// ---------------------------------------------------------------------------
// Scan phase 1: per-chunk (prodA, h_end), channel-per-thread, h[8] in regs.
// ---------------------------------------------------------------------------
__global__ __launch_bounds__(256) void scan1_k(const float* __restrict__ delta,
    const float* __restrict__ uc, const float* __restrict__ dbc,
    const float* __restrict__ A_log, float* __restrict__ cA,
    float* __restrict__ cH) {
  const int c = blockIdx.y, b = blockIdx.z;
  const int e  = blockIdx.x*128 + (threadIdx.x >> 1);
  const int n0 = (threadIdx.x & 1) * 8;
  const float4 a0 = *(const float4*)(A_log + e*NN + n0);
  const float4 a1 = *(const float4*)(A_log + e*NN + n0 + 4);
  float Aen[8] = {-__expf(a0.x), -__expf(a0.y), -__expf(a0.z), -__expf(a0.w),
                  -__expf(a1.x), -__expf(a1.y), -__expf(a1.z), -__expf(a1.w)};
  float h[8] = {};
  float sumd = 0.f;
  const size_t tok0 = (size_t)b*LL + (size_t)c*LC;
  for (int i = 0; i < LC; i++) {
    const size_t t = tok0 + i;
    const float dv = delta[t*ED + e];
    const float uv = uc[t*ED + e];
    const float du = dv * uv;
    const float4 B0 = *(const float4*)(dbc + t*40 + RR + n0);
    const float4 B1 = *(const float4*)(dbc + t*40 + RR + n0 + 4);
    const float Bv[8] = {B0.x,B0.y,B0.z,B0.w,B1.x,B1.y,B1.z,B1.w};
    sumd += dv;
    #pragma unroll
    for (int j = 0; j < 8; j++) {
      const float dA = __expf(dv * Aen[j]);
      h[j] = dA*h[j] + Bv[j]*du;
    }
  }
  const size_t base = (((size_t)c*BB + b)*ED + e)*NN + n0;
  *(float4*)(cA + base)     = make_float4(__expf(sumd*Aen[0]), __expf(sumd*Aen[1]),
                                          __expf(sumd*Aen[2]), __expf(sumd*Aen[3]));
  *(float4*)(cA + base + 4) = make_float4(__expf(sumd*Aen[4]), __expf(sumd*Aen[5]),
                                          __expf(sumd*Aen[6]), __expf(sumd*Aen[7]));
  *(float4*)(cH + base)     = make_float4(h[0], h[1], h[2], h[3]);
  *(float4*)(cH + base + 4) = make_float4(h[4], h[5], h[6], h[7]);
}

// ---------------------------------------------------------------------------
// Scan phase 2: scan over NC chunk summaries, in-place prefix into cA.
// ---------------------------------------------------------------------------
__global__ __launch_bounds__(256) void scan2_k(float* __restrict__ cA,
    const float* __restrict__ cH) {
  const int gt = blockIdx.x*256 + threadIdx.x;   // [0, BB*ED*NN)
  const int b = gt >> 12;
  const size_t base = (size_t)b*ED*NN + (gt & 4095);
  float h = 0.f;
  for (int c = 0; c < NC; c++) {
    const size_t idx = (size_t)c*(BB*ED*NN) + base;
    const float a = cA[idx], hh = cH[idx];
    cA[idx] = h;               // prefix (carry-in for chunk c)
    h = a*h + hh;
  }
}

// ---------------------------------------------------------------------------
// Scan phase 3: replay with prefix, in-register n-reduction (+1 shuffle),
// fused gating: y = (scan_y + u*Dp) * silu(z). Output bf16 (feeds out_proj).
// ---------------------------------------------------------------------------
__global__ __launch_bounds__(256) void scan3_k(const float* __restrict__ delta,
    const float* __restrict__ uc, const float* __restrict__ dbc,
    const float* __restrict__ xz, const float* __restrict__ A_log,
    const float* __restrict__ Dpv, const float* __restrict__ cP,
    unsigned short* __restrict__ ybf) {
  const int c = blockIdx.y, b = blockIdx.z;
  const int e    = blockIdx.x*128 + (threadIdx.x >> 1);
  const int half = threadIdx.x & 1;
  const int n0   = half * 8;
  const float4 a0 = *(const float4*)(A_log + e*NN + n0);
  const float4 a1 = *(const float4*)(A_log + e*NN + n0 + 4);
  float Aen[8] = {-__expf(a0.x), -__expf(a0.y), -__expf(a0.z), -__expf(a0.w),
                  -__expf(a1.x), -__expf(a1.y), -__expf(a1.z), -__expf(a1.w)};
  const float Dpe = Dpv[e];
  const size_t base = (((size_t)c*BB + b)*ED + e)*NN + n0;
  const float4 h0 = *(const float4*)(cP + base);
  const float4 h1 = *(const float4*)(cP + base + 4);
  float h[8] = {h0.x,h0.y,h0.z,h0.w,h1.x,h1.y,h1.z,h1.w};
  const size_t tok0 = (size_t)b*LL + (size_t)c*LC;
  for (int i = 0; i < LC; i++) {
    const size_t t = tok0 + i;
    const float dv = delta[t*ED + e];
    const float uv = uc[t*ED + e];
    const float du = dv * uv;
    const float4 B0 = *(const float4*)(dbc + t*40 + RR + n0);
    const float4 B1 = *(const float4*)(dbc + t*40 + RR + n0 + 4);
    const float4 C0 = *(const float4*)(dbc + t*40 + RR + NN + n0);
    const float4 C1 = *(const float4*)(dbc + t*40 + RR + NN + n0 + 4);
    const float Bv[8] = {B0.x,B0.y,B0.z,B0.w,B1.x,B1.y,B1.z,B1.w};
    const float Cv[8] = {C0.x,C0.y,C0.z,C0.w,C1.x,C1.y,C1.z,C1.w};
    float part = 0.f;
    #pragma unroll
    for (int j = 0; j < 8; j++) {
      const float dA = __expf(dv * Aen[j]);
      h[j] = dA*h[j] + Bv[j]*du;
      part += h[j]*Cv[j];
    }
    part += __shfl_xor(part, 1);       // combine the two n-halves
    if (half == 0) {
      const float zv = xz[t*(2*ED) + ED + e];
      const float g = zv / (1.f + __expf(-zv));   // silu(z)
      ybf[t*ED + e] = f2bf((part + uv*Dpe) * g);
    }
  }
}

// ---------------------------------------------------------------------------
extern "C" void kernel_launch(void* const* d_in, const int* in_sizes, int n_in,
                              void* d_out, int out_size, void* d_ws, size_t ws_size,
                              hipStream_t stream) {
  const float* x      = (const float*)d_in[0];
  const float* n1g    = (const float*)d_in[1];
  const float* n1b    = (const float*)d_in[2];
  const float* ing    = (const float*)d_in[3];
  const float* inb    = (const float*)d_in[4];
  const float* in_w   = (const float*)d_in[5];
  const float* conv_w = (const float*)d_in[6];
  const float* conv_b = (const float*)d_in[7];
  const float* xproj_w= (const float*)d_in[8];
  const float* dt_w   = (const float*)d_in[9];
  const float* dt_b   = (const float*)d_in[10];
  const float* A_log  = (const float*)d_in[11];
  const float* Dpv    = (const float*)d_in[12];
  const float* out_w  = (const float*)d_in[13];
  const float* fc1_w  = (const float*)d_in[14];
  const float* fc1_b  = (const float*)d_in[15];
  const float* fc2_w  = (const float*)d_in[16];
  const float* fc2_b  = (const float*)d_in[17];
  float* out = (float*)d_out;

  // Workspace layout. fp32 arrays first, then bf16 arrays. ~62 MB total.
  float* ws    = (float*)d_ws;
  float* xz    = ws;                          // [NT,512]
  float* uc    = xz    + (size_t)NT*2*ED;     // [NT,256]
  float* dbc   = uc    + (size_t)NT*ED;       // [NT,40]
  float* delta = dbc   + (size_t)NT*40;       // [NT,256]
  float* cAP   = delta + (size_t)NT*ED;       // [NC,B,ED,N]
  float* cH    = cAP   + (size_t)NC*BB*ED*NN;
  float* xnew  = cH    + (size_t)NC*BB*ED*NN; // [NT,128]
  unsigned short* xnbf  = (unsigned short*)(xnew + (size_t)NT*DD);
  unsigned short* ybf   = xnbf  + (size_t)NT*DD;   // [NT,256] bf16
  unsigned short* hlnbf = ybf   + (size_t)NT*ED;   // [NT,128] bf16
  unsigned short* hmlbf = hlnbf + (size_t)NT*DD;   // [NT,256] bf16
  unsigned short* wbin  = hmlbf + (size_t)NT*HH;   // 512x128 bf16
  unsigned short* wbout = wbin  + (size_t)2*ED*DD; // 128x256
  unsigned short* wbf1  = wbout + (size_t)DD*ED;   // 256x128
  unsigned short* wbf2  = wbf1  + (size_t)HH*DD;   // 128x256

  // 0) weights -> bf16 (once per launch)
  cvt4_k<<<160, 256, 0, stream>>>(in_w, out_w, fc1_w, fc2_w, wbin, wbout, wbf1, wbf2);
  // 1) xnbf = bf16(inner_ln(norm1(x)))
  ln2_k<true><<<NT/4, 256, 0, stream>>>(x, n1g, n1b, ing, inb, xnbf);
  // 2) xz = xn @ in_w^T   [NT,512]
  gemm_bf_k<DD,0,float><<<dim3(512/64, NT/64), 256, 0, stream>>>(xnbf, wbin, nullptr, nullptr, xz, 2*ED);
  // 3) fused conv+silu, x_proj, delta
  cxd2_k<<<NT/16, 256, 0, stream>>>(xz, conv_w, conv_b, xproj_w, dt_w, dt_b, uc, dbc, delta);
  // 4-6) chunked selective scan + gating -> ybf
  scan1_k<<<dim3(2, NC, BB), 256, 0, stream>>>(delta, uc, dbc, A_log, cAP, cH);
  scan2_k<<<(BB*ED*NN)/256, 256, 0, stream>>>(cAP, cH);
  scan3_k<<<dim3(2, NC, BB), 256, 0, stream>>>(delta, uc, dbc, xz, A_log, Dpv, cAP, ybf);
  // 7) xnew = y @ out_w^T + x
  gemm_bf_k<ED,1,float><<<dim3(DD/64, NT/64), 256, 0, stream>>>(ybf, wbout, nullptr, x, xnew, DD);
  // 8) hlnbf = bf16(norm1(xnew))
  ln2_k<false><<<NT/4, 256, 0, stream>>>(xnew, n1g, n1b, nullptr, nullptr, hlnbf);
  // 9) hmlbf = bf16(gelu(hln @ fc1_w^T + fc1_b))
  gemm_bf_k<DD,2,unsigned short><<<dim3(HH/64, NT/64), 256, 0, stream>>>(hlnbf, wbf1, fc1_b, nullptr, hmlbf, HH);
  // 10) out = hmlp @ fc2_w^T + fc2_b + xnew
  gemm_bf_k<HH,3,float><<<dim3(DD/64, NT/64), 256, 0, stream>>>(hmlbf, wbf2, fc2_b, xnew, out, DD);
}

// Round 5
// 189.078 us; speedup vs baseline: 1.6083x; 1.1458x over previous
//
#include <hip/hip_runtime.h>
#include <hip/hip_bf16.h>
#include <math.h>

// Problem constants (match reference)
#define BB 2
#define LL 4096
#define DD 128
#define ED 256
#define NN 16
#define KK 4
#define RR 8
#define HH 256
#define NT (BB*LL)          // 8192 tokens
#define NC 128              // chunks for scan
#define LC 32               // chunk length (NC*LC == LL)

typedef __attribute__((ext_vector_type(8))) short short8;
typedef __attribute__((ext_vector_type(8))) unsigned short ushort8v;
typedef __attribute__((ext_vector_type(4))) float floatx4;

__device__ __forceinline__ unsigned short f2bf(float f) {
  unsigned int b = __builtin_bit_cast(unsigned int, f);
  b += 0x7FFFu + ((b >> 16) & 1u);           // round-to-nearest-even
  return (unsigned short)(b >> 16);
}

// ---------------------------------------------------------------------------
// One-shot fp32->bf16 conversion of the 5 weight matrices used by MFMA paths.
// float4 units: in_w 16384 | out_w 8192 | fc1 8192 | fc2 8192 | xproj 2560
// total 43520 -> 170 blocks x 256.
// ---------------------------------------------------------------------------
__global__ __launch_bounds__(256) void cvt5_k(const float* __restrict__ a,
    const float* __restrict__ b, const float* __restrict__ c,
    const float* __restrict__ d, const float* __restrict__ e5,
    unsigned short* __restrict__ oa, unsigned short* __restrict__ ob,
    unsigned short* __restrict__ oc, unsigned short* __restrict__ od,
    unsigned short* __restrict__ oe) {
  const int i = blockIdx.x*256 + threadIdx.x;   // < 43520 float4s
  const float* src; unsigned short* dst; int off;
  if (i < 16384)      { src = a;  dst = oa; off = i; }
  else if (i < 24576) { src = b;  dst = ob; off = i - 16384; }
  else if (i < 32768) { src = c;  dst = oc; off = i - 24576; }
  else if (i < 40960) { src = d;  dst = od; off = i - 32768; }
  else                { src = e5; dst = oe; off = i - 40960; }
  const float4 v = ((const float4*)src)[off];
  unsigned int lo = f2bf(v.x) | ((unsigned int)f2bf(v.y) << 16);
  unsigned int hi = f2bf(v.z) | ((unsigned int)f2bf(v.w) << 16);
  ((uint2*)dst)[off] = make_uint2(lo, hi);
}

// ---------------------------------------------------------------------------
// LayerNorm, wave-per-token, bf16 output (feeds GEMM A-operand only).
// ---------------------------------------------------------------------------
template<bool DOUBLE>
__global__ __launch_bounds__(256) void ln2_k(const float* __restrict__ x,
    const float* __restrict__ g1, const float* __restrict__ b1,
    const float* __restrict__ g2, const float* __restrict__ b2,
    unsigned short* __restrict__ out) {
  const int token = blockIdx.x*4 + (threadIdx.x >> 6);
  const int lane  = threadIdx.x & 63;
  float2 v = *(const float2*)(x + (size_t)token*DD + lane*2);

  auto wsum = [&](float s) -> float {
    s += __shfl_xor(s, 32); s += __shfl_xor(s, 16); s += __shfl_xor(s, 8);
    s += __shfl_xor(s, 4);  s += __shfl_xor(s, 2);  s += __shfl_xor(s, 1);
    return s;
  };

  float mean = wsum(v.x + v.y) * (1.f/128.f);
  float cx = v.x - mean, cy = v.y - mean;
  float var = wsum(cx*cx + cy*cy) * (1.f/128.f);
  float rs = rsqrtf(var + 1e-5f);
  const float2 g = *(const float2*)(g1 + lane*2);
  const float2 bb = *(const float2*)(b1 + lane*2);
  float yx = cx*rs*g.x + bb.x;
  float yy = cy*rs*g.y + bb.y;
  if constexpr (DOUBLE) {
    float m2 = wsum(yx + yy) * (1.f/128.f);
    float c2x = yx - m2, c2y = yy - m2;
    float v2 = wsum(c2x*c2x + c2y*c2y) * (1.f/128.f);
    float rs2 = rsqrtf(v2 + 1e-5f);
    const float2 g2v = *(const float2*)(g2 + lane*2);
    const float2 b2v = *(const float2*)(b2 + lane*2);
    yx = c2x*rs2*g2v.x + b2v.x;
    yy = c2y*rs2*g2v.y + b2v.y;
  }
  const unsigned int packed = f2bf(yx) | ((unsigned int)f2bf(yy) << 16);
  *(unsigned int*)(out + (size_t)token*DD + lane*2) = packed;
}

// ---------------------------------------------------------------------------
// bf16 MFMA GEMM: C[M,Nn] = A[M,KD] @ W[Nn,KD]^T; A,W pre-converted bf16.
// 64x64 tile, 4 waves (2x2 of 32x32), 16x16x32 fragments.
// EPI: 0 = none; 1 = +res; 2 = gelu(+bias); 3 = +bias +res
// ---------------------------------------------------------------------------
template<int KD, int EPI, typename OT>
__global__ __launch_bounds__(256) void gemm_bf_k(
    const unsigned short* __restrict__ A, const unsigned short* __restrict__ W,
    const float* __restrict__ bias, const float* __restrict__ res,
    OT* __restrict__ C, int Nn) {
  static_assert(KD % 128 == 0, "KD multiple of 128");
  __shared__ unsigned short As[64][136];   // 64 rows x 128 bf16, pad 8
  __shared__ unsigned short Ws[64][136];

  const int row0 = blockIdx.y * 64;
  const int col0 = blockIdx.x * 64;
  const int tid  = threadIdx.x;
  const int wave = tid >> 6;
  const int lane = tid & 63;
  const int quad = lane >> 4;
  const int l16  = lane & 15;
  const int wm = (wave & 1) * 32;
  const int wn = (wave >> 1) * 32;
  const int lr = tid >> 2;            // staging row 0..63
  const int lc = (tid & 3) * 32;      // staging col (32 bf16 = 64 B)

  floatx4 acc[2][2] = {};

  for (int ks0 = 0; ks0 < KD; ks0 += 128) {
    const unsigned short* Ap = A + (size_t)(row0 + lr)*KD + ks0 + lc;
    const unsigned short* Wp = W + (size_t)(col0 + lr)*KD + ks0 + lc;
    ushort8v av[4], wv[4];
    #pragma unroll
    for (int g = 0; g < 4; g++) {
      av[g] = *(const ushort8v*)(Ap + g*8);
      wv[g] = *(const ushort8v*)(Wp + g*8);
    }
    __syncthreads();
    #pragma unroll
    for (int g = 0; g < 4; g++) {
      *(ushort8v*)&As[lr][lc + g*8] = av[g];
      *(ushort8v*)&Ws[lr][lc + g*8] = wv[g];
    }
    __syncthreads();
    #pragma unroll
    for (int ks = 0; ks < 4; ks++) {
      const int ko = ks*32 + quad*8;
      short8 a0 = *(const short8*)&As[wm +      l16][ko];
      short8 a1 = *(const short8*)&As[wm + 16 + l16][ko];
      short8 b0 = *(const short8*)&Ws[wn +      l16][ko];
      short8 b1 = *(const short8*)&Ws[wn + 16 + l16][ko];
      acc[0][0] = __builtin_amdgcn_mfma_f32_16x16x32_bf16(a0, b0, acc[0][0], 0, 0, 0);
      acc[0][1] = __builtin_amdgcn_mfma_f32_16x16x32_bf16(a0, b1, acc[0][1], 0, 0, 0);
      acc[1][0] = __builtin_amdgcn_mfma_f32_16x16x32_bf16(a1, b0, acc[1][0], 0, 0, 0);
      acc[1][1] = __builtin_amdgcn_mfma_f32_16x16x32_bf16(a1, b1, acc[1][1], 0, 0, 0);
    }
  }

  #pragma unroll
  for (int i = 0; i < 2; i++) {
    #pragma unroll
    for (int j = 0; j < 2; j++) {
      const int n = col0 + wn + j*16 + l16;
      float bn = 0.f;
      if constexpr (EPI == 2 || EPI == 3) bn = bias[n];
      #pragma unroll
      for (int r = 0; r < 4; r++) {
        const int m = row0 + wm + i*16 + quad*4 + r;
        float v = acc[i][j][r];
        if constexpr (EPI == 2 || EPI == 3) v += bn;
        if constexpr (EPI == 2) v = 0.5f*v*(1.f + erff(v*0.70710678118f));
        const size_t o = (size_t)m*Nn + n;
        if constexpr (EPI == 1 || EPI == 3) v += res[o];
        if constexpr (sizeof(OT) == 2) C[o] = (OT)f2bf(v);
        else                           C[o] = v;
      }
    }
  }
}

// ---------------------------------------------------------------------------
// Fused middle: causal conv(K=4)+bias+silu -> xproj (bf16 MFMA) -> delta.
// 32 tokens per block, 256 blocks. No scattered global loads: xproj weights
// staged coalesced into LDS (rows 40..63 zero), u-tile written to LDS in
// MFMA A-layout by the conv phase.
// Writes uc [NT,ED] fp32, dbc [NT,40] fp32, delta [NT,ED] fp32.
// ---------------------------------------------------------------------------
__global__ __launch_bounds__(256) void mamba_mid_k(const float* __restrict__ xz,
    const float* __restrict__ cw, const float* __restrict__ cb,
    const unsigned short* __restrict__ xpwb, const float* __restrict__ dtw,
    const float* __restrict__ dtb, float* __restrict__ uc,
    float* __restrict__ dbc, float* __restrict__ delta) {
  __shared__ unsigned short As[32][264];   // u-tile, MFMA A layout (tok x k)
  __shared__ unsigned short Bs[64][264];   // xproj weights (n x k), 40 real
  __shared__ float sd[32][8];              // dt columns for delta phase
  const int t0  = blockIdx.x * 32;         // 4096 % 32 == 0: no batch cross
  const int tid = threadIdx.x;

  // --- stage xproj weights (coalesced; rows >= 40 zeroed) ---
  #pragma unroll
  for (int p = 0; p < 8; p++) {
    const int idx = p*256 + tid;           // 2048 chunks of 8 shorts
    const int row = idx >> 5;              // 32 chunks per 256-col row
    const int col = (idx & 31) * 8;
    ushort8v v = {};
    if (row < 40) v = *(const ushort8v*)(xpwb + row*ED + col);
    *(ushort8v*)&Bs[row][col] = v;
  }

  // --- conv: rolling window, one channel per thread ---
  const int e = tid;
  const float4 w = *(const float4*)(cw + e*4);
  const float cbe = cb[e];
  float h0 = 0.f, h1 = 0.f, h2 = 0.f;
  if (t0 & 4095) {
    h0 = xz[(size_t)(t0-3)*(2*ED) + e];
    h1 = xz[(size_t)(t0-2)*(2*ED) + e];
    h2 = xz[(size_t)(t0-1)*(2*ED) + e];
  }
  #pragma unroll 4
  for (int i = 0; i < 32; i++) {
    const float cur = xz[(size_t)(t0+i)*(2*ED) + e];
    const float a = cbe + h0*w.x + h1*w.y + h2*w.z + cur*w.w;
    const float s = a / (1.f + __expf(-a));
    As[i][e] = f2bf(s);
    uc[(size_t)(t0+i)*ED + e] = s;
    h0 = h1; h1 = h2; h2 = cur;
  }
  __syncthreads();

  // --- xproj MFMA: M=32 (2 m-frags), N=64 (4 n-frags), K=256 (8 ksteps) ---
  const int wave = tid >> 6, lane = tid & 63;
  const int quad = lane >> 4, l16 = lane & 15;
  const int mi = (wave & 1) * 16;          // m-frag base
  const int j0 = (wave >> 1) * 2;          // first of 2 n-frags
  floatx4 acc[2] = {};
  #pragma unroll
  for (int ks = 0; ks < 8; ks++) {
    const int ko = ks*32 + quad*8;
    short8 a  = *(const short8*)&As[mi + l16][ko];
    short8 b0 = *(const short8*)&Bs[j0*16 +      l16][ko];
    short8 b1 = *(const short8*)&Bs[j0*16 + 16 + l16][ko];
    acc[0] = __builtin_amdgcn_mfma_f32_16x16x32_bf16(a, b0, acc[0], 0, 0, 0);
    acc[1] = __builtin_amdgcn_mfma_f32_16x16x32_bf16(a, b1, acc[1], 0, 0, 0);
  }
  #pragma unroll
  for (int f = 0; f < 2; f++) {
    const int n = (j0 + f)*16 + l16;
    #pragma unroll
    for (int r = 0; r < 4; r++) {
      const int m = mi + quad*4 + r;
      const float v = acc[f][r];
      if (n < 40) dbc[(size_t)(t0 + m)*40 + n] = v;
      if (n < RR) sd[m][n] = v;
    }
  }
  __syncthreads();

  // --- delta: softplus(dt @ dt_w^T + dt_b), one channel per thread ---
  const float4 w0 = *(const float4*)(dtw + e*RR);
  const float4 w1 = *(const float4*)(dtw + e*RR + 4);
  const float db = dtb[e];
  #pragma unroll 4
  for (int t = 0; t < 32; t++) {
    const float a = db
        + sd[t][0]*w0.x + sd[t][1]*w0.y + sd[t][2]*w0.z + sd[t][3]*w0.w
        + sd[t][4]*w1.x + sd[t][5]*w1.y + sd[t][6]*w1.z + sd[t][7]*w1.w;
    delta[(size_t)(t0+t)*ED + e] = (a > 20.f) ? a : log1pf(__expf(a));
  }
}

// ---------------------------------------------------------------------------
// Scan phase 1: per-chunk (prodA, h_end), channel-per-thread, h[8] in regs.
// ---------------------------------------------------------------------------
__global__ __launch_bounds__(256) void scan1_k(const float* __restrict__ delta,
    const float* __restrict__ uc, const float* __restrict__ dbc,
    const float* __restrict__ A_log, float* __restrict__ cA,
    float* __restrict__ cH) {
  const int c = blockIdx.y, b = blockIdx.z;
  const int e  = blockIdx.x*128 + (threadIdx.x >> 1);
  const int n0 = (threadIdx.x & 1) * 8;
  const float4 a0 = *(const float4*)(A_log + e*NN + n0);
  const float4 a1 = *(const float4*)(A_log + e*NN + n0 + 4);
  float Aen[8] = {-__expf(a0.x), -__expf(a0.y), -__expf(a0.z), -__expf(a0.w),
                  -__expf(a1.x), -__expf(a1.y), -__expf(a1.z), -__expf(a1.w)};
  float h[8] = {};
  float sumd = 0.f;
  const size_t tok0 = (size_t)b*LL + (size_t)c*LC;
  for (int i = 0; i < LC; i++) {
    const size_t t = tok0 + i;
    const float dv = delta[t*ED + e];
    const float uv = uc[t*ED + e];
    const float du = dv * uv;
    const float4 B0 = *(const float4*)(dbc + t*40 + RR + n0);
    const float4 B1 = *(const float4*)(dbc + t*40 + RR + n0 + 4);
    const float Bv[8] = {B0.x,B0.y,B0.z,B0.w,B1.x,B1.y,B1.z,B1.w};
    sumd += dv;
    #pragma unroll
    for (int j = 0; j < 8; j++) {
      const float dA = __expf(dv * Aen[j]);
      h[j] = dA*h[j] + Bv[j]*du;
    }
  }
  const size_t base = (((size_t)c*BB + b)*ED + e)*NN + n0;
  *(float4*)(cA + base)     = make_float4(__expf(sumd*Aen[0]), __expf(sumd*Aen[1]),
                                          __expf(sumd*Aen[2]), __expf(sumd*Aen[3]));
  *(float4*)(cA + base + 4) = make_float4(__expf(sumd*Aen[4]), __expf(sumd*Aen[5]),
                                          __expf(sumd*Aen[6]), __expf(sumd*Aen[7]));
  *(float4*)(cH + base)     = make_float4(h[0], h[1], h[2], h[3]);
  *(float4*)(cH + base + 4) = make_float4(h[4], h[5], h[6], h[7]);
}

// ---------------------------------------------------------------------------
// Scan phase 2: scan over NC chunk summaries, in-place prefix into cA.
// ---------------------------------------------------------------------------
__global__ __launch_bounds__(256) void scan2_k(float* __restrict__ cA,
    const float* __restrict__ cH) {
  const int gt = blockIdx.x*256 + threadIdx.x;   // [0, BB*ED*NN)
  const int b = gt >> 12;
  const size_t base = (size_t)b*ED*NN + (gt & 4095);
  float h = 0.f;
  for (int c = 0; c < NC; c++) {
    const size_t idx = (size_t)c*(BB*ED*NN) + base;
    const float a = cA[idx], hh = cH[idx];
    cA[idx] = h;               // prefix (carry-in for chunk c)
    h = a*h + hh;
  }
}

// ---------------------------------------------------------------------------
// Scan phase 3: replay with prefix, in-register n-reduction (+1 shuffle),
// fused gating: y = (scan_y + u*Dp) * silu(z). Output bf16 (feeds out_proj).
// ---------------------------------------------------------------------------
__global__ __launch_bounds__(256) void scan3_k(const float* __restrict__ delta,
    const float* __restrict__ uc, const float* __restrict__ dbc,
    const float* __restrict__ xz, const float* __restrict__ A_log,
    const float* __restrict__ Dpv, const float* __restrict__ cP,
    unsigned short* __restrict__ ybf) {
  const int c = blockIdx.y, b = blockIdx.z;
  const int e    = blockIdx.x*128 + (threadIdx.x >> 1);
  const int half = threadIdx.x & 1;
  const int n0   = half * 8;
  const float4 a0 = *(const float4*)(A_log + e*NN + n0);
  const float4 a1 = *(const float4*)(A_log + e*NN + n0 + 4);
  float Aen[8] = {-__expf(a0.x), -__expf(a0.y), -__expf(a0.z), -__expf(a0.w),
                  -__expf(a1.x), -__expf(a1.y), -__expf(a1.z), -__expf(a1.w)};
  const float Dpe = Dpv[e];
  const size_t base = (((size_t)c*BB + b)*ED + e)*NN + n0;
  const float4 h0 = *(const float4*)(cP + base);
  const float4 h1 = *(const float4*)(cP + base + 4);
  float h[8] = {h0.x,h0.y,h0.z,h0.w,h1.x,h1.y,h1.z,h1.w};
  const size_t tok0 = (size_t)b*LL + (size_t)c*LC;
  for (int i = 0; i < LC; i++) {
    const size_t t = tok0 + i;
    const float dv = delta[t*ED + e];
    const float uv = uc[t*ED + e];
    const float du = dv * uv;
    const float4 B0 = *(const float4*)(dbc + t*40 + RR + n0);
    const float4 B1 = *(const float4*)(dbc + t*40 + RR + n0 + 4);
    const float4 C0 = *(const float4*)(dbc + t*40 + RR + NN + n0);
    const float4 C1 = *(const float4*)(dbc + t*40 + RR + NN + n0 + 4);
    const float Bv[8] = {B0.x,B0.y,B0.z,B0.w,B1.x,B1.y,B1.z,B1.w};
    const float Cv[8] = {C0.x,C0.y,C0.z,C0.w,C1.x,C1.y,C1.z,C1.w};
    float part = 0.f;
    #pragma unroll
    for (int j = 0; j < 8; j++) {
      const float dA = __expf(dv * Aen[j]);
      h[j] = dA*h[j] + Bv[j]*du;
      part += h[j]*Cv[j];
    }
    part += __shfl_xor(part, 1);       // combine the two n-halves
    if (half == 0) {
      const float zv = xz[t*(2*ED) + ED + e];
      const float g = zv / (1.f + __expf(-zv));   // silu(z)
      ybf[t*ED + e] = f2bf((part + uv*Dpe) * g);
    }
  }
}

// ---------------------------------------------------------------------------
extern "C" void kernel_launch(void* const* d_in, const int* in_sizes, int n_in,
                              void* d_out, int out_size, void* d_ws, size_t ws_size,
                              hipStream_t stream) {
  const float* x      = (const float*)d_in[0];
  const float* n1g    = (const float*)d_in[1];
  const float* n1b    = (const float*)d_in[2];
  const float* ing    = (const float*)d_in[3];
  const float* inb    = (const float*)d_in[4];
  const float* in_w   = (const float*)d_in[5];
  const float* conv_w = (const float*)d_in[6];
  const float* conv_b = (const float*)d_in[7];
  const float* xproj_w= (const float*)d_in[8];
  const float* dt_w   = (const float*)d_in[9];
  const float* dt_b   = (const float*)d_in[10];
  const float* A_log  = (const float*)d_in[11];
  const float* Dpv    = (const float*)d_in[12];
  const float* out_w  = (const float*)d_in[13];
  const float* fc1_w  = (const float*)d_in[14];
  const float* fc1_b  = (const float*)d_in[15];
  const float* fc2_w  = (const float*)d_in[16];
  const float* fc2_b  = (const float*)d_in[17];
  float* out = (float*)d_out;

  // Workspace layout. fp32 arrays first, then bf16 arrays. ~62 MB total.
  float* ws    = (float*)d_ws;
  float* xz    = ws;                          // [NT,512]
  float* uc    = xz    + (size_t)NT*2*ED;     // [NT,256]
  float* dbc   = uc    + (size_t)NT*ED;       // [NT,40]
  float* delta = dbc   + (size_t)NT*40;       // [NT,256]
  float* cAP   = delta + (size_t)NT*ED;       // [NC,B,ED,N]
  float* cH    = cAP   + (size_t)NC*BB*ED*NN;
  float* xnew  = cH    + (size_t)NC*BB*ED*NN; // [NT,128]
  unsigned short* xnbf  = (unsigned short*)(xnew + (size_t)NT*DD);
  unsigned short* ybf   = xnbf  + (size_t)NT*DD;   // [NT,256] bf16
  unsigned short* hlnbf = ybf   + (size_t)NT*ED;   // [NT,128] bf16
  unsigned short* hmlbf = hlnbf + (size_t)NT*DD;   // [NT,256] bf16
  unsigned short* wbin  = hmlbf + (size_t)NT*HH;   // 512x128 bf16
  unsigned short* wbout = wbin  + (size_t)2*ED*DD; // 128x256
  unsigned short* wbf1  = wbout + (size_t)DD*ED;   // 256x128
  unsigned short* wbf2  = wbf1  + (size_t)HH*DD;   // 128x256
  unsigned short* wbxp  = wbf2  + (size_t)DD*HH;   // 40x256

  // 0) weights -> bf16 (once per launch)
  cvt5_k<<<170, 256, 0, stream>>>(in_w, out_w, fc1_w, fc2_w, xproj_w,
                                  wbin, wbout, wbf1, wbf2, wbxp);
  // 1) xnbf = bf16(inner_ln(norm1(x)))
  ln2_k<true><<<NT/4, 256, 0, stream>>>(x, n1g, n1b, ing, inb, xnbf);
  // 2) xz = xn @ in_w^T   [NT,512]
  gemm_bf_k<DD,0,float><<<dim3(512/64, NT/64), 256, 0, stream>>>(xnbf, wbin, nullptr, nullptr, xz, 2*ED);
  // 3) fused conv+silu -> xproj(MFMA) -> delta
  mamba_mid_k<<<NT/32, 256, 0, stream>>>(xz, conv_w, conv_b, wbxp, dt_w, dt_b, uc, dbc, delta);
  // 4-6) chunked selective scan + gating -> ybf
  scan1_k<<<dim3(2, NC, BB), 256, 0, stream>>>(delta, uc, dbc, A_log, cAP, cH);
  scan2_k<<<(BB*ED*NN)/256, 256, 0, stream>>>(cAP, cH);
  scan3_k<<<dim3(2, NC, BB), 256, 0, stream>>>(delta, uc, dbc, xz, A_log, Dpv, cAP, ybf);
  // 7) xnew = y @ out_w^T + x
  gemm_bf_k<ED,1,float><<<dim3(DD/64, NT/64), 256, 0, stream>>>(ybf, wbout, nullptr, x, xnew, DD);
  // 8) hlnbf = bf16(norm1(xnew))
  ln2_k<false><<<NT/4, 256, 0, stream>>>(xnew, n1g, n1b, nullptr, nullptr, hlnbf);
  // 9) hmlbf = bf16(gelu(hln @ fc1_w^T + fc1_b))
  gemm_bf_k<DD,2,unsigned short><<<dim3(HH/64, NT/64), 256, 0, stream>>>(hlnbf, wbf1, fc1_b, nullptr, hmlbf, HH);
  // 10) out = hmlp @ fc2_w^T + fc2_b + xnew
  gemm_bf_k<HH,3,float><<<dim3(DD/64, NT/64), 256, 0, stream>>>(hmlbf, wbf2, fc2_b, xnew, out, DD);
}